// Round 1
// 7181.078 us; speedup vs baseline: 1.4122x; 1.4122x over previous
//
#include <hip/hip_runtime.h>
#include <math.h>

#define N 8192
#define DIM 64
#define CAP_E 2000000

typedef unsigned long long u64;
typedef unsigned int u32;
typedef unsigned short u16;

// ---------------- zero the output buffer (births stay 0) -----------------------
__global__ void zero_out_kernel(float* __restrict__ out, int n) {
    int i = blockIdx.x * blockDim.x + threadIdx.x;
    if (i < n) out[i] = 0.0f;
}

// ---------------- canonical norms: ni = sum fmaf(x_k, x_k) ascending k ---------
__global__ __launch_bounds__(256) void norms_kernel(const float* __restrict__ x,
                                                    float* __restrict__ norms) {
    int i = blockIdx.x * blockDim.x + threadIdx.x;
    const float* row = x + (size_t)i * DIM;
    float acc = 0.f;
    #pragma unroll
    for (int k = 0; k < DIM; k++) { float v = row[k]; acc = __builtin_fmaf(v, v, acc); }
    norms[i] = acc;
}

// ---------------- canonical tile machinery (shared by scan & collect) ----------
__device__ inline void stage_tiles(const float* __restrict__ x, int bi, int bj, int t,
                                   float (*As)[64], float (*Bs)[64]) {
    int r = t >> 2, c0 = (t & 3) * 16;
    const float4* pa = (const float4*)(x + (size_t)(bi * 64 + r) * DIM + c0);
    const float4* pb = (const float4*)(x + (size_t)(bj * 64 + r) * DIM + c0);
    #pragma unroll
    for (int q = 0; q < 4; q++) {
        float4 a = pa[q], b = pb[q];
        int c = c0 + q * 4;
        As[c + 0][r] = a.x; As[c + 1][r] = a.y; As[c + 2][r] = a.z; As[c + 3][r] = a.w;
        Bs[c + 0][r] = b.x; Bs[c + 1][r] = b.y; Bs[c + 2][r] = b.z; Bs[c + 3][r] = b.w;
    }
}

__device__ inline void tile_d2(const float (*As)[64], const float (*Bs)[64],
                               const float ni[4], const float nj[4],
                               int tx, int ty, u32 d2b[4][4]) {
    float acc[4][4] = {};
    #pragma unroll 4
    for (int k = 0; k < 64; k++) {
        float av[4], bv[4];
        #pragma unroll
        for (int r = 0; r < 4; r++) av[r] = As[k][ty * 4 + r];
        #pragma unroll
        for (int c = 0; c < 4; c++) bv[c] = Bs[k][tx * 4 + c];
        #pragma unroll
        for (int r = 0; r < 4; r++)
            #pragma unroll
            for (int c = 0; c < 4; c++)
                acc[r][c] = __builtin_fmaf(av[r], bv[c], acc[r][c]);
    }
    #pragma unroll
    for (int r = 0; r < 4; r++)
        #pragma unroll
        for (int c = 0; c < 4; c++) {
            float d2 = __builtin_fmaf(-2.0f, acc[r][c], ni[r] + nj[c]);
            d2 = d2 < 0.f ? 0.f : d2;
            d2b[r][c] = __float_as_uint(d2);
        }
}

// ---------------- init ---------------------------------------------------------
// ctr[0]=mstCount ctr[1]=done ctr[2]=flag ctr[3]=edgeCount
__global__ void init_kernel(u64* bestR, u64* bestC, u16* comp16, u32* deg, u32* ctr) {
    int i = blockIdx.x * blockDim.x + threadIdx.x;
    if (i < 8192) { bestR[i] = ~0ull; bestC[i] = ~0ull; comp16[i] = (u16)i; deg[i] = 0; }
    if (i < 8) ctr[i] = 0;
}

// ---------------- Boruvka fused scan: recompute tile + per-row best ------------
__global__ __launch_bounds__(256) void scan_fused(const float* __restrict__ x,
                                                  const float* __restrict__ norms,
                                                  const u16* __restrict__ comp16,
                                                  u64* __restrict__ bestR,
                                                  const u32* __restrict__ ctr) {
    if (ctr[1]) return;
    int bi = blockIdx.y, bj = blockIdx.x;
    if (bj < bi) return;
    __shared__ float As[64][64], Bs[64][64];
    __shared__ u16 rc[64], cc[64];
    __shared__ u64 rowBest[64], colBest[64];
    int t = threadIdx.x;
    stage_tiles(x, bi, bj, t, As, Bs);
    if (t < 64) {
        rc[t] = comp16[bi * 64 + t];
        cc[t] = comp16[bj * 64 + t];
        rowBest[t] = ~0ull; colBest[t] = ~0ull;
    }
    __syncthreads();
    int tx = t & 15, ty = t >> 4;
    float ni[4], nj[4];
    #pragma unroll
    for (int r = 0; r < 4; r++) ni[r] = norms[bi * 64 + ty * 4 + r];
    #pragma unroll
    for (int c = 0; c < 4; c++) nj[c] = norms[bj * 64 + tx * 4 + c];
    u32 d2b[4][4];
    tile_d2(As, Bs, ni, nj, tx, ty, d2b);

    #pragma unroll
    for (int r = 0; r < 4; r++) {
        u16 rcv = rc[ty * 4 + r];
        int gi = bi * 64 + ty * 4 + r;
        u64 best = ~0ull;
        #pragma unroll
        for (int c = 0; c < 4; c++) {
            if (cc[tx * 4 + c] != rcv) {
                int gj = bj * 64 + tx * 4 + c;
                u32 lo = gi < gj ? (u32)gi : (u32)gj;
                u32 hi = gi < gj ? (u32)gj : (u32)gi;
                u64 key = ((u64)d2b[r][c] << 26) | ((u64)lo << 13) | hi;
                if (key < best) best = key;
            }
        }
        if (best != ~0ull) atomicMin(&rowBest[ty * 4 + r], best);
    }
    #pragma unroll
    for (int c = 0; c < 4; c++) {
        u16 ccv = cc[tx * 4 + c];
        int gj = bj * 64 + tx * 4 + c;
        u64 best = ~0ull;
        #pragma unroll
        for (int r = 0; r < 4; r++) {
            if (rc[ty * 4 + r] != ccv) {
                int gi = bi * 64 + ty * 4 + r;
                u32 lo = gi < gj ? (u32)gi : (u32)gj;
                u32 hi = gi < gj ? (u32)gj : (u32)gi;
                u64 key = ((u64)d2b[r][c] << 26) | ((u64)lo << 13) | hi;
                if (key < best) best = key;
            }
        }
        if (best != ~0ull) atomicMin(&colBest[tx * 4 + c], best);
    }
    __syncthreads();
    if (t < 64) {
        if (rowBest[t] != ~0ull) atomicMin(&bestR[bi * 64 + t], rowBest[t]);
        if (colBest[t] != ~0ull) atomicMin(&bestR[bj * 64 + t], colBest[t]);
    }
}

// ---------------- fold rows -> components --------------------------------------
__global__ void fold_kernel(u64* bestR, u64* bestC, const u16* comp16, const u32* ctr) {
    if (ctr[1]) return;
    int i = blockIdx.x * blockDim.x + threadIdx.x;
    if (i < 8192) {
        u64 k = bestR[i];
        if (k != ~0ull) { atomicMin(&bestC[comp16[i]], k); bestR[i] = ~0ull; }
    }
}

// ---------------- Boruvka merge ------------------------------------------------
__global__ __launch_bounds__(1024) void merge_kernel(u16* comp16, u64* bestC,
                                                     u64* mstKeys, u32* ctr) {
    __shared__ u16 ping[8192], pong[8192];
    __shared__ unsigned char act[8192];
    __shared__ u32 cnt_s;
    if (ctr[1]) return;
    int t = threadIdx.x;
    if (t == 0) cnt_s = 0;
    for (int c = t; c < 8192; c += 1024) {
        u64 key = bestC[c];
        u16 par = (u16)c;
        if (key != ~0ull) {
            u32 a = (u32)(key >> 13) & 8191u, b = (u32)key & 8191u;
            u16 ca = comp16[a];
            u16 cv = (ca == (u16)c) ? comp16[b] : ca;
            u64 k2 = bestC[cv];
            bool mutual = false;
            if (k2 != ~0ull) {
                u32 a2 = (u32)(k2 >> 13) & 8191u, b2 = (u32)k2 & 8191u;
                u16 ca2 = comp16[a2];
                u16 cv2 = (ca2 == cv) ? comp16[b2] : ca2;
                mutual = (cv2 == (u16)c);
            }
            par = cv;
            if (mutual && (u32)c < (u32)cv) par = (u16)c;
            bool add = (!mutual) || ((u32)c < (u32)cv);
            if (add) {
                u32 idx = atomicAdd(&ctr[0], 1u);
                if (idx < 8192u) mstKeys[idx] = key;
            }
        }
        ping[c] = par;
        act[c] = 0;
    }
    __syncthreads();
    for (int c = t; c < 8192; c += 1024) bestC[c] = ~0ull;   // reset for next round
    __syncthreads();
    for (int it = 0; it < 13; it++) {
        for (int c = t; c < 8192; c += 1024) pong[c] = ping[ping[c]];
        __syncthreads();
        for (int c = t; c < 8192; c += 1024) ping[c] = pong[c];
        __syncthreads();
    }
    for (int v = t; v < 8192; v += 1024) {
        u16 nc = ping[comp16[v]];
        comp16[v] = nc;
        act[nc] = 1;
    }
    __syncthreads();
    u32 local = 0;
    for (int c = t; c < 8192; c += 1024) local += act[c];
    atomicAdd(&cnt_s, local);
    __syncthreads();
    if (t == 0 && cnt_s == 1) ctr[1] = 1;
}

// ---------------- bitonic sort -> sorted d2 bit-patterns -----------------------
__global__ __launch_bounds__(1024) void sort_kernel(const u64* __restrict__ mstKeys,
                                                    u32* __restrict__ sortedWB,
                                                    const u32* __restrict__ ctr) {
    __shared__ u64 keys[8192];
    int t = threadIdx.x;
    u32 m = ctr[0]; if (m > 8191u) m = 8191u;
    for (int i = t; i < 8192; i += 1024) keys[i] = (i < (int)m) ? mstKeys[i] : ~0ull;
    __syncthreads();
    for (u32 k = 2; k <= 8192; k <<= 1)
        for (u32 j = k >> 1; j > 0; j >>= 1) {
            for (int i = t; i < 8192; i += 1024) {
                u32 ixj = (u32)i ^ j;
                if (ixj > (u32)i) {
                    u64 a = keys[i], b = keys[ixj];
                    bool up = ((i & k) == 0);
                    if ((a > b) == up) { keys[i] = b; keys[ixj] = a; }
                }
            }
            __syncthreads();
        }
    for (int i = t; i < 8192; i += 1024)
        sortedWB[i] = (i < 8191) ? (u32)(keys[i] >> 26) : 0xFFFFFFFFu;
}

// ---------------- collect G' = all pairs whose d2 equals an MST weight ---------
__global__ __launch_bounds__(256) void collect_kernel(const float* __restrict__ x,
                                                      const float* __restrict__ norms,
                                                      const u32* __restrict__ sortedWB,
                                                      u64* __restrict__ edges,
                                                      u32* __restrict__ ctr) {
    __shared__ float As[64][64], Bs[64][64];
    __shared__ u32 sw[8191];
    int bi = blockIdx.y, bj = blockIdx.x;
    if (bj < bi) return;
    int t = threadIdx.x;
    stage_tiles(x, bi, bj, t, As, Bs);
    for (int i = t; i < 8191; i += 256) sw[i] = sortedWB[i];
    __syncthreads();
    u32 wmin = sw[0], wmax = sw[8190];
    int tx = t & 15, ty = t >> 4;
    float ni[4], nj[4];
    #pragma unroll
    for (int r = 0; r < 4; r++) ni[r] = norms[bi * 64 + ty * 4 + r];
    #pragma unroll
    for (int c = 0; c < 4; c++) nj[c] = norms[bj * 64 + tx * 4 + c];
    u32 d2b[4][4];
    tile_d2(As, Bs, ni, nj, tx, ty, d2b);

    #pragma unroll
    for (int r = 0; r < 4; r++) {
        int gi = bi * 64 + ty * 4 + r;
        #pragma unroll
        for (int c = 0; c < 4; c++) {
            int gj = bj * 64 + tx * 4 + c;
            if (gj <= gi) continue;
            u32 wb = d2b[r][c];
            if (wb < wmin || wb > wmax) continue;
            int lo = 0, hi = 8190;
            while (lo < hi) { int mid = (lo + hi) >> 1; if (sw[mid] < wb) lo = mid + 1; else hi = mid; }
            if (sw[lo] == wb) {
                u32 idx = atomicAdd(&ctr[3], 1u);
                if (idx < CAP_E)
                    edges[idx] = ((u64)(u32)lo << 26) | ((u64)(u32)gi << 13) | (u32)gj;
                else
                    atomicOr(&ctr[2], 16u);
            }
        }
    }
}

// ---------------- degree count -------------------------------------------------
__global__ void degcnt_kernel(const u64* __restrict__ edges, u32* __restrict__ deg,
                              const u32* __restrict__ ctr) {
    u32 m = ctr[3]; if (m > CAP_E) m = CAP_E;
    for (u32 idx = blockIdx.x * 256u + threadIdx.x; idx < m; idx += gridDim.x * 256u) {
        u64 e = edges[idx];
        atomicAdd(&deg[(u32)(e >> 13) & 8191u], 1u);
        atomicAdd(&deg[(u32)e & 8191u], 1u);
    }
}

// ---------------- prefix sum: offs[8193] + cur ---------------------------------
__global__ __launch_bounds__(1024) void offs_kernel(const u32* __restrict__ deg,
                                                    u32* __restrict__ offs,
                                                    u32* __restrict__ cur) {
    __shared__ u32 partial[1024];
    int t = threadIdx.x;
    u32 loc[8], s = 0;
    #pragma unroll
    for (int e = 0; e < 8; e++) { loc[e] = deg[t * 8 + e]; s += loc[e]; }
    partial[t] = s;
    __syncthreads();
    for (int d = 1; d < 1024; d <<= 1) {
        u32 v = (t >= d) ? partial[t - d] : 0;
        __syncthreads();
        partial[t] += v;
        __syncthreads();
    }
    u32 run = t ? partial[t - 1] : 0;
    #pragma unroll
    for (int e = 0; e < 8; e++) { offs[t * 8 + e] = run; cur[t * 8 + e] = run; run += loc[e]; }
    if (t == 1023) offs[8192] = run;
}

// ---------------- fill adjacency: entry = rank(13)<<13 | far(13) ---------------
__global__ void fill_kernel(const u64* __restrict__ edges, u32* __restrict__ cur,
                            u32* __restrict__ adj, const u32* __restrict__ ctr) {
    u32 m = ctr[3]; if (m > CAP_E) m = CAP_E;
    for (u32 idx = blockIdx.x * 256u + threadIdx.x; idx < m; idx += gridDim.x * 256u) {
        u64 e = edges[idx];
        u32 rk = (u32)(e >> 26) & 8191u;
        u32 i = (u32)(e >> 13) & 8191u, j = (u32)e & 8191u;
        u32 p1 = atomicAdd(&cur[i], 1u); adj[p1] = (rk << 13) | j;
        u32 p2 = atomicAdd(&cur[j], 1u); adj[p2] = (rk << 13) | i;
    }
}

// ---------------- wave64 min-reduce via DPP (result valid in lane 63) ----------
__device__ __forceinline__ u32 dpp_min_u32(u32 x) {
    u32 y;
    y = (u32)__builtin_amdgcn_update_dpp((int)0xFFFFFFFF, (int)x, 0x111, 0xf, 0xf, false); x = y < x ? y : x;
    y = (u32)__builtin_amdgcn_update_dpp((int)0xFFFFFFFF, (int)x, 0x112, 0xf, 0xf, false); x = y < x ? y : x;
    y = (u32)__builtin_amdgcn_update_dpp((int)0xFFFFFFFF, (int)x, 0x114, 0xf, 0xf, false); x = y < x ? y : x;
    y = (u32)__builtin_amdgcn_update_dpp((int)0xFFFFFFFF, (int)x, 0x118, 0xf, 0xf, false); x = y < x ? y : x;
    y = (u32)__builtin_amdgcn_update_dpp((int)0xFFFFFFFF, (int)x, 0x142, 0xa, 0xf, false); x = y < x ? y : x;
    y = (u32)__builtin_amdgcn_update_dpp((int)0xFFFFFFFF, (int)x, 0x143, 0xc, 0xf, false); x = y < x ? y : x;
    return x;
}

// ---------------- exact sparse Prim on G' — DPP reduce + LDS-resident graph ----
// Semantics identical to previous version: pop key = rank(13)<<13 | vertex(13),
// min-key pop == reference's (value, first-index) argmin. Per-lane `cmin` caches
// the exact min key over its 128 owned vertices; each step the popped vertex's
// owner row is rescanned (reads distributed across the wave, DPP-reduced) while
// a second DPP chain reduces cached minima + freshly inserted candidates.
// sMind[v]: u16 best rank; 0x3FFF = empty, 0xFFFF = in-tree.
__global__ __launch_bounds__(256) void gprim_kernel(const u32* __restrict__ offs,
                                                    const u32* __restrict__ adjG,
                                                    u32* __restrict__ seqv,
                                                    u32* __restrict__ ctr) {
    __shared__ u16 sMind[8192];      // 16 KB, row L = vertices {L, L+64, ...}, loc = L*128+slot
    __shared__ u32 sOffs[8193];      // 32 KB
    __shared__ u32 sAdj[16384];      // 64 KB (fits the generic |E'| = n-1 tree case)
    const int t = threadIdx.x;
    for (int i = t; i < 8193; i += 256) sOffs[i] = offs[i];
    { u32* p = (u32*)sMind; for (int i = t; i < 4096; i += 256) p[i] = 0x3FFF3FFFu; }
    u32 m = ctr[3]; if (m > CAP_E) m = CAP_E;
    u32 tot = 2u * m;
    const bool useLds = (tot <= 16384u);
    if (useLds) {
        const uint4* a4 = (const uint4*)adjG; uint4* s4 = (uint4*)sAdj;
        u32 tot4 = (tot + 3u) >> 2;
        for (u32 i = (u32)t; i < tot4; i += 256u) s4[i] = a4[i];
    }
    __syncthreads();
    if (t >= 64) return;                       // one wave runs the serial Prim
    const int lane = t;
    if (lane == 0) sMind[0] = 0xFFFFu;         // vertex 0 in tree
    u64 ins0 = (lane == 0) ? 1ull : 0ull, ins1 = 0ull;  // in-tree bits for my 128 vertices
    u32 cmin = 0xFFFFFFFFu;
    u32 v = 0u, Lv = 0u;                       // current in-tree vertex + its owner lane

#define PROC(e, pred) do { \
        u32 _far = (e) & 8191u, _rk = (e) >> 13; \
        if ((pred) && (((_far ^ (u32)lane) & 63u) == 0u)) { \
            u32 _slot = _far >> 6; \
            u64 _w = (_slot & 64u) ? ins1 : ins0; \
            if (((_w >> (_slot & 63u)) & 1ull) == 0ull) { \
                u32 _k = (_rk << 13) | _far; \
                if (_k < patch) patch = _k; \
                u32 _loc = ((u32)lane << 7) + _slot; \
                u16 _old = sMind[_loc]; \
                if ((u16)_rk < _old) sMind[_loc] = (u16)_rk; \
            } \
        } \
    } while (0)

    for (int step = 0; step < N - 1; ++step) {
        // ---- cooperative read of owner row Lv (2 slots/lane, conflict-free) ----
        u32 rowPair = ((const u32*)sMind)[(Lv << 6) + (u32)lane];
        // ---- adjacency of v (wave-uniform broadcast reads, batched 4-wide) ----
        u32 o0 = sOffs[v], o1 = sOffs[v + 1];
        u32 dg = o1 - o0;
        u32 iL = (o1 > o0) ? (o1 - 1u) : o0;
        u32 patch = 0xFFFFFFFFu;               // my accepted candidates this step
        {
            u32 i1 = (o0 + 1u > iL) ? iL : o0 + 1u;
            u32 i2 = (o0 + 2u > iL) ? iL : o0 + 2u;
            u32 i3 = (o0 + 3u > iL) ? iL : o0 + 3u;
            u32 e0, e1, e2, e3;
            if (useLds) { e0 = sAdj[o0]; e1 = sAdj[i1]; e2 = sAdj[i2]; e3 = sAdj[i3]; }
            else        { e0 = adjG[o0]; e1 = adjG[i1]; e2 = adjG[i2]; e3 = adjG[i3]; }
            PROC(e0, dg > 0u); PROC(e1, dg > 1u); PROC(e2, dg > 2u); PROC(e3, dg > 3u);
            for (u32 q = 4u; q < dg; ++q) {
                u32 e = useLds ? sAdj[o0 + q] : adjG[o0 + q];
                PROC(e, true);
            }
        }
        cmin = patch < cmin ? patch : cmin;    // keep cached row min exact (non-owner lanes)
        // ---- row keys: mask empty/in-tree and the just-popped v ----
        u32 m0 = rowPair & 0xFFFFu, m1 = rowPair >> 16;
        u32 s0 = ((u32)lane << 1), s1 = s0 + 1u;
        u32 vslot = v >> 6;
        u32 k0 = (m0 < 0x3FFFu && s0 != vslot) ? ((m0 << 13) | (s0 << 6) | Lv) : 0xFFFFFFFFu;
        u32 k1 = (m1 < 0x3FFFu && s1 != vslot) ? ((m1 << 13) | (s1 << 6) | Lv) : 0xFFFFFFFFu;
        u32 rowMin = k0 < k1 ? k0 : k1;
        // ---- two concurrent DPP chains: R = row-Lv rescan, C = cached mins ----
        u32 R = dpp_min_u32(rowMin);
        u32 xc = ((u32)lane == Lv) ? patch : cmin;   // exclude stale cmin of Lv
        u32 C = dpp_min_u32(xc);
        u32 Rs = (u32)__builtin_amdgcn_readlane((int)R, 63);
        u32 Cs = (u32)__builtin_amdgcn_readlane((int)C, 63);
        u32 g = Rs < Cs ? Rs : Cs;
        if ((u32)lane == Lv) cmin = Rs < patch ? Rs : patch;  // restore exactness
        if (g >= (0x3FFFu << 13)) { if (lane == 0) atomicOr(&ctr[2], 2u); break; }
        if (lane == 0) seqv[step] = g;
        // ---- mark popped vertex in tree ----
        v = g & 8191u; Lv = v & 63u;
        if ((u32)lane == Lv) {
            u32 nslot = v >> 6;
            if (nslot < 64u) ins0 |= 1ull << nslot; else ins1 |= 1ull << (nslot - 64u);
            sMind[(Lv << 7) + nslot] = 0xFFFFu;
        }
    }
#undef PROC
}

// ---------------- gather: deaths = sqrt(d2 of popped rank) ---------------------
__global__ void gather_kernel(const u32* __restrict__ seqv,
                              const u32* __restrict__ sortedWB,
                              float* __restrict__ out) {
    int s = blockIdx.x * blockDim.x + threadIdx.x;
    if (s < N - 1) {
        u32 p = seqv[s];
        u32 rk = p >> 13;
        out[2 * s + 1] = sqrtf(__uint_as_float(sortedWB[rk]));
    }
}

extern "C" void kernel_launch(void* const* d_in, const int* in_sizes, int n_in,
                              void* d_out, int out_size, void* d_ws, size_t ws_size,
                              hipStream_t stream) {
    const float* x = (const float*)d_in[0];
    float* out = (float*)d_out;

    char* ws = (char*)d_ws;
    size_t o = 0;
    u64* bestR    = (u64*)(ws + o); o += 8192 * 8;            // 64 KB
    u64* bestC    = (u64*)(ws + o); o += 8192 * 8;            // 64 KB
    u64* mstKeys  = (u64*)(ws + o); o += 8192 * 8;            // 64 KB
    u64* edges    = (u64*)(ws + o); o += (size_t)CAP_E * 8;   // 16 MB
    float* norms  = (float*)(ws + o); o += 8192 * 4;
    u32* sortedWB = (u32*)(ws + o); o += 8192 * 4;
    u32* deg      = (u32*)(ws + o); o += 8192 * 4;
    u32* offs     = (u32*)(ws + o); o += 8200 * 4;
    u32* cur      = (u32*)(ws + o); o += 8192 * 4;
    u32* seqv     = (u32*)(ws + o); o += 8192 * 4;
    u32* adj      = (u32*)(ws + o); o += (size_t)CAP_E * 2 * 4; // 16 MB
    u16* comp16   = (u16*)(ws + o); o += 8192 * 2;
    u32* ctr      = (u32*)(ws + o); o += 256;
    // total ~33 MB << 256 MiB

    zero_out_kernel<<<(out_size + 255) / 256, 256, 0, stream>>>(out, out_size);
    norms_kernel<<<32, 256, 0, stream>>>(x, norms);
    init_kernel<<<32, 256, 0, stream>>>(bestR, bestC, comp16, deg, ctr);

    for (int r = 0; r < 13; r++) {
        scan_fused<<<dim3(128, 128), 256, 0, stream>>>(x, norms, comp16, bestR, ctr);
        fold_kernel<<<32, 256, 0, stream>>>(bestR, bestC, comp16, ctr);
        merge_kernel<<<1, 1024, 0, stream>>>(comp16, bestC, mstKeys, ctr);
    }

    sort_kernel<<<1, 1024, 0, stream>>>(mstKeys, sortedWB, ctr);
    collect_kernel<<<dim3(128, 128), 256, 0, stream>>>(x, norms, sortedWB, edges, ctr);
    degcnt_kernel<<<512, 256, 0, stream>>>(edges, deg, ctr);
    offs_kernel<<<1, 1024, 0, stream>>>(deg, offs, cur);
    fill_kernel<<<512, 256, 0, stream>>>(edges, cur, adj, ctr);
    gprim_kernel<<<1, 256, 0, stream>>>(offs, adj, seqv, ctr);
    gather_kernel<<<32, 256, 0, stream>>>(seqv, sortedWB, out);
}

// Round 2
// 6256.300 us; speedup vs baseline: 1.6209x; 1.1478x over previous
//
#include <hip/hip_runtime.h>
#include <math.h>

#define N 8192
#define DIM 64
#define CAP_E 2000000

typedef unsigned long long u64;
typedef unsigned int u32;
typedef unsigned short u16;

// ---------------- zero the output buffer (births stay 0) -----------------------
__global__ void zero_out_kernel(float* __restrict__ out, int n) {
    int i = blockIdx.x * blockDim.x + threadIdx.x;
    if (i < n) out[i] = 0.0f;
}

// ---------------- canonical norms: ni = sum fmaf(x_k, x_k) ascending k ---------
__global__ __launch_bounds__(256) void norms_kernel(const float* __restrict__ x,
                                                    float* __restrict__ norms) {
    int i = blockIdx.x * blockDim.x + threadIdx.x;
    const float* row = x + (size_t)i * DIM;
    float acc = 0.f;
    #pragma unroll
    for (int k = 0; k < DIM; k++) { float v = row[k]; acc = __builtin_fmaf(v, v, acc); }
    norms[i] = acc;
}

// ---------------- canonical tile machinery (shared by scan & collect) ----------
// [64][65] padding: write-phase bank conflicts drop 4-way -> 2-way (free).
__device__ inline void stage_tiles(const float* __restrict__ x, int bi, int bj, int t,
                                   float (*As)[65], float (*Bs)[65]) {
    int r = t >> 2, c0 = (t & 3) * 16;
    const float4* pa = (const float4*)(x + (size_t)(bi * 64 + r) * DIM + c0);
    const float4* pb = (const float4*)(x + (size_t)(bj * 64 + r) * DIM + c0);
    #pragma unroll
    for (int q = 0; q < 4; q++) {
        float4 a = pa[q], b = pb[q];
        int c = c0 + q * 4;
        As[c + 0][r] = a.x; As[c + 1][r] = a.y; As[c + 2][r] = a.z; As[c + 3][r] = a.w;
        Bs[c + 0][r] = b.x; Bs[c + 1][r] = b.y; Bs[c + 2][r] = b.z; Bs[c + 3][r] = b.w;
    }
}

__device__ inline void tile_d2(const float (*As)[65], const float (*Bs)[65],
                               const float ni[4], const float nj[4],
                               int tx, int ty, u32 d2b[4][4]) {
    float acc[4][4] = {};
    #pragma unroll 4
    for (int k = 0; k < 64; k++) {
        float av[4], bv[4];
        #pragma unroll
        for (int r = 0; r < 4; r++) av[r] = As[k][ty * 4 + r];
        #pragma unroll
        for (int c = 0; c < 4; c++) bv[c] = Bs[k][tx * 4 + c];
        #pragma unroll
        for (int r = 0; r < 4; r++)
            #pragma unroll
            for (int c = 0; c < 4; c++)
                acc[r][c] = __builtin_fmaf(av[r], bv[c], acc[r][c]);
    }
    #pragma unroll
    for (int r = 0; r < 4; r++)
        #pragma unroll
        for (int c = 0; c < 4; c++) {
            float d2 = __builtin_fmaf(-2.0f, acc[r][c], ni[r] + nj[c]);
            d2 = d2 < 0.f ? 0.f : d2;
            d2b[r][c] = __float_as_uint(d2);
        }
}

// ---------------- init ---------------------------------------------------------
// ctr[0]=mstCount ctr[1]=done ctr[2]=flag ctr[3]=edgeCount
__global__ void init_kernel(u64* bestR, u64* bestC, u16* comp16, u32* deg, u32* ctr) {
    int i = blockIdx.x * blockDim.x + threadIdx.x;
    if (i < 8192) { bestR[i] = ~0ull; bestC[i] = ~0ull; comp16[i] = (u16)i; deg[i] = 0; }
    if (i < 8) ctr[i] = 0;
}

// ---------------- Boruvka fused scan: recompute tile + per-row best ------------
__global__ __launch_bounds__(256) void scan_fused(const float* __restrict__ x,
                                                  const float* __restrict__ norms,
                                                  const u16* __restrict__ comp16,
                                                  u64* __restrict__ bestR,
                                                  const u32* __restrict__ ctr) {
    if (ctr[1]) return;
    int bi = blockIdx.y, bj = blockIdx.x;
    if (bj < bi) return;
    __shared__ float As[64][65], Bs[64][65];
    __shared__ u16 rc[64], cc[64];
    __shared__ u64 rowBest[64], colBest[64];
    int t = threadIdx.x;
    stage_tiles(x, bi, bj, t, As, Bs);
    if (t < 64) {
        rc[t] = comp16[bi * 64 + t];
        cc[t] = comp16[bj * 64 + t];
        rowBest[t] = ~0ull; colBest[t] = ~0ull;
    }
    __syncthreads();
    int tx = t & 15, ty = t >> 4;
    float ni[4], nj[4];
    #pragma unroll
    for (int r = 0; r < 4; r++) ni[r] = norms[bi * 64 + ty * 4 + r];
    #pragma unroll
    for (int c = 0; c < 4; c++) nj[c] = norms[bj * 64 + tx * 4 + c];
    u32 d2b[4][4];
    tile_d2(As, Bs, ni, nj, tx, ty, d2b);

    #pragma unroll
    for (int r = 0; r < 4; r++) {
        u16 rcv = rc[ty * 4 + r];
        int gi = bi * 64 + ty * 4 + r;
        u64 best = ~0ull;
        #pragma unroll
        for (int c = 0; c < 4; c++) {
            if (cc[tx * 4 + c] != rcv) {
                int gj = bj * 64 + tx * 4 + c;
                u32 lo = gi < gj ? (u32)gi : (u32)gj;
                u32 hi = gi < gj ? (u32)gj : (u32)gi;
                u64 key = ((u64)d2b[r][c] << 26) | ((u64)lo << 13) | hi;
                if (key < best) best = key;
            }
        }
        if (best != ~0ull) atomicMin(&rowBest[ty * 4 + r], best);
    }
    #pragma unroll
    for (int c = 0; c < 4; c++) {
        u16 ccv = cc[tx * 4 + c];
        int gj = bj * 64 + tx * 4 + c;
        u64 best = ~0ull;
        #pragma unroll
        for (int r = 0; r < 4; r++) {
            if (rc[ty * 4 + r] != ccv) {
                int gi = bi * 64 + ty * 4 + r;
                u32 lo = gi < gj ? (u32)gi : (u32)gj;
                u32 hi = gi < gj ? (u32)gj : (u32)gi;
                u64 key = ((u64)d2b[r][c] << 26) | ((u64)lo << 13) | hi;
                if (key < best) best = key;
            }
        }
        if (best != ~0ull) atomicMin(&colBest[tx * 4 + c], best);
    }
    __syncthreads();
    if (t < 64) {
        if (rowBest[t] != ~0ull) atomicMin(&bestR[bi * 64 + t], rowBest[t]);
        if (colBest[t] != ~0ull) atomicMin(&bestR[bj * 64 + t], colBest[t]);
    }
}

// ---------------- fold rows -> components --------------------------------------
__global__ void fold_kernel(u64* bestR, u64* bestC, const u16* comp16, const u32* ctr) {
    if (ctr[1]) return;
    int i = blockIdx.x * blockDim.x + threadIdx.x;
    if (i < 8192) {
        u64 k = bestR[i];
        if (k != ~0ull) { atomicMin(&bestC[comp16[i]], k); bestR[i] = ~0ull; }
    }
}

// ---------------- Boruvka merge ------------------------------------------------
__global__ __launch_bounds__(1024) void merge_kernel(u16* comp16, u64* bestC,
                                                     u64* mstKeys, u32* ctr) {
    __shared__ u16 ping[8192], pong[8192];
    __shared__ unsigned char act[8192];
    __shared__ u32 cnt_s;
    if (ctr[1]) return;
    int t = threadIdx.x;
    if (t == 0) cnt_s = 0;
    for (int c = t; c < 8192; c += 1024) {
        u64 key = bestC[c];
        u16 par = (u16)c;
        if (key != ~0ull) {
            u32 a = (u32)(key >> 13) & 8191u, b = (u32)key & 8191u;
            u16 ca = comp16[a];
            u16 cv = (ca == (u16)c) ? comp16[b] : ca;
            u64 k2 = bestC[cv];
            bool mutual = false;
            if (k2 != ~0ull) {
                u32 a2 = (u32)(k2 >> 13) & 8191u, b2 = (u32)k2 & 8191u;
                u16 ca2 = comp16[a2];
                u16 cv2 = (ca2 == cv) ? comp16[b2] : ca2;
                mutual = (cv2 == (u16)c);
            }
            par = cv;
            if (mutual && (u32)c < (u32)cv) par = (u16)c;
            bool add = (!mutual) || ((u32)c < (u32)cv);
            if (add) {
                u32 idx = atomicAdd(&ctr[0], 1u);
                if (idx < 8192u) mstKeys[idx] = key;
            }
        }
        ping[c] = par;
        act[c] = 0;
    }
    __syncthreads();
    for (int c = t; c < 8192; c += 1024) bestC[c] = ~0ull;   // reset for next round
    __syncthreads();
    for (int it = 0; it < 13; it++) {
        for (int c = t; c < 8192; c += 1024) pong[c] = ping[ping[c]];
        __syncthreads();
        for (int c = t; c < 8192; c += 1024) ping[c] = pong[c];
        __syncthreads();
    }
    for (int v = t; v < 8192; v += 1024) {
        u16 nc = ping[comp16[v]];
        comp16[v] = nc;
        act[nc] = 1;
    }
    __syncthreads();
    u32 local = 0;
    for (int c = t; c < 8192; c += 1024) local += act[c];
    atomicAdd(&cnt_s, local);
    __syncthreads();
    if (t == 0 && cnt_s == 1) ctr[1] = 1;
}

// ---------------- bitonic sort -> sorted d2 bit-patterns -----------------------
__global__ __launch_bounds__(1024) void sort_kernel(const u64* __restrict__ mstKeys,
                                                    u32* __restrict__ sortedWB,
                                                    const u32* __restrict__ ctr) {
    __shared__ u64 keys[8192];
    int t = threadIdx.x;
    u32 m = ctr[0]; if (m > 8191u) m = 8191u;
    for (int i = t; i < 8192; i += 1024) keys[i] = (i < (int)m) ? mstKeys[i] : ~0ull;
    __syncthreads();
    for (u32 k = 2; k <= 8192; k <<= 1)
        for (u32 j = k >> 1; j > 0; j >>= 1) {
            for (int i = t; i < 8192; i += 1024) {
                u32 ixj = (u32)i ^ j;
                if (ixj > (u32)i) {
                    u64 a = keys[i], b = keys[ixj];
                    bool up = ((i & k) == 0);
                    if ((a > b) == up) { keys[i] = b; keys[ixj] = a; }
                }
            }
            __syncthreads();
        }
    for (int i = t; i < 8192; i += 1024)
        sortedWB[i] = (i < 8191) ? (u32)(keys[i] >> 26) : 0xFFFFFFFFu;
}

// ---------------- collect G' = all pairs whose d2 equals an MST weight ---------
__global__ __launch_bounds__(256) void collect_kernel(const float* __restrict__ x,
                                                      const float* __restrict__ norms,
                                                      const u32* __restrict__ sortedWB,
                                                      u64* __restrict__ edges,
                                                      u32* __restrict__ ctr) {
    __shared__ float As[64][65], Bs[64][65];
    __shared__ u32 sw[8191];
    int bi = blockIdx.y, bj = blockIdx.x;
    if (bj < bi) return;
    int t = threadIdx.x;
    stage_tiles(x, bi, bj, t, As, Bs);
    for (int i = t; i < 8191; i += 256) sw[i] = sortedWB[i];
    __syncthreads();
    u32 wmin = sw[0], wmax = sw[8190];
    int tx = t & 15, ty = t >> 4;
    float ni[4], nj[4];
    #pragma unroll
    for (int r = 0; r < 4; r++) ni[r] = norms[bi * 64 + ty * 4 + r];
    #pragma unroll
    for (int c = 0; c < 4; c++) nj[c] = norms[bj * 64 + tx * 4 + c];
    u32 d2b[4][4];
    tile_d2(As, Bs, ni, nj, tx, ty, d2b);

    #pragma unroll
    for (int r = 0; r < 4; r++) {
        int gi = bi * 64 + ty * 4 + r;
        #pragma unroll
        for (int c = 0; c < 4; c++) {
            int gj = bj * 64 + tx * 4 + c;
            if (gj <= gi) continue;
            u32 wb = d2b[r][c];
            if (wb < wmin || wb > wmax) continue;
            int lo = 0, hi = 8190;
            while (lo < hi) { int mid = (lo + hi) >> 1; if (sw[mid] < wb) lo = mid + 1; else hi = mid; }
            if (sw[lo] == wb) {
                u32 idx = atomicAdd(&ctr[3], 1u);
                if (idx < CAP_E)
                    edges[idx] = ((u64)(u32)lo << 26) | ((u64)(u32)gi << 13) | (u32)gj;
                else
                    atomicOr(&ctr[2], 16u);
            }
        }
    }
}

// ---------------- degree count -------------------------------------------------
__global__ void degcnt_kernel(const u64* __restrict__ edges, u32* __restrict__ deg,
                              const u32* __restrict__ ctr) {
    u32 m = ctr[3]; if (m > CAP_E) m = CAP_E;
    for (u32 idx = blockIdx.x * 256u + threadIdx.x; idx < m; idx += gridDim.x * 256u) {
        u64 e = edges[idx];
        atomicAdd(&deg[(u32)(e >> 13) & 8191u], 1u);
        atomicAdd(&deg[(u32)e & 8191u], 1u);
    }
}

// ---------------- prefix sum: offs[8193] + cur ---------------------------------
__global__ __launch_bounds__(1024) void offs_kernel(const u32* __restrict__ deg,
                                                    u32* __restrict__ offs,
                                                    u32* __restrict__ cur) {
    __shared__ u32 partial[1024];
    int t = threadIdx.x;
    u32 loc[8], s = 0;
    #pragma unroll
    for (int e = 0; e < 8; e++) { loc[e] = deg[t * 8 + e]; s += loc[e]; }
    partial[t] = s;
    __syncthreads();
    for (int d = 1; d < 1024; d <<= 1) {
        u32 v = (t >= d) ? partial[t - d] : 0;
        __syncthreads();
        partial[t] += v;
        __syncthreads();
    }
    u32 run = t ? partial[t - 1] : 0;
    #pragma unroll
    for (int e = 0; e < 8; e++) { offs[t * 8 + e] = run; cur[t * 8 + e] = run; run += loc[e]; }
    if (t == 1023) offs[8192] = run;
}

// ---------------- fill adjacency: entry = rank(13)<<13 | far(13) ---------------
__global__ void fill_kernel(const u64* __restrict__ edges, u32* __restrict__ cur,
                            u32* __restrict__ adj, const u32* __restrict__ ctr) {
    u32 m = ctr[3]; if (m > CAP_E) m = CAP_E;
    for (u32 idx = blockIdx.x * 256u + threadIdx.x; idx < m; idx += gridDim.x * 256u) {
        u64 e = edges[idx];
        u32 rk = (u32)(e >> 26) & 8191u;
        u32 i = (u32)(e >> 13) & 8191u, j = (u32)e & 8191u;
        u32 p1 = atomicAdd(&cur[i], 1u); adj[p1] = (rk << 13) | j;
        u32 p2 = atomicAdd(&cur[j], 1u); adj[p2] = (rk << 13) | i;
    }
}

// ---------------- pack adjacency: 4 inline slots + rare overflow ---------------
// adj4[v] = {e0,e1,e2,e3} padded with 0xFFFFFFFF; deg>4 -> 3 inline + marker
// 0xFFFFFFFE in .w, extras read from CSR (ovf[v] = dg<<32 | o0) on demand.
// Valid entries are < 2^26, so "pred = e < 0x04000000" filters pad/marker.
__global__ __launch_bounds__(256) void adj4_kernel(const u32* __restrict__ offs,
                                                   const u32* __restrict__ adjG,
                                                   uint4* __restrict__ adj4,
                                                   u64* __restrict__ ovf) {
    int v = blockIdx.x * 256 + threadIdx.x;
    if (v >= N) return;
    u32 o0 = offs[v], o1 = offs[v + 1], dg = o1 - o0;
    u32 e[4] = {0xFFFFFFFFu, 0xFFFFFFFFu, 0xFFFFFFFFu, 0xFFFFFFFFu};
    u32 nin = dg <= 4u ? dg : 3u;
    for (u32 q = 0; q < nin; q++) e[q] = adjG[o0 + q];
    if (dg > 4u) e[3] = 0xFFFFFFFEu;
    adj4[v] = make_uint4(e[0], e[1], e[2], e[3]);
    ovf[v] = ((u64)dg << 32) | o0;
}

// ---------------- wave64 min-reduce via DPP (result valid in lane 63) ----------
__device__ __forceinline__ u32 dpp_min_u32(u32 x) {
    u32 y;
    y = (u32)__builtin_amdgcn_update_dpp((int)0xFFFFFFFF, (int)x, 0x111, 0xf, 0xf, false); x = y < x ? y : x;
    y = (u32)__builtin_amdgcn_update_dpp((int)0xFFFFFFFF, (int)x, 0x112, 0xf, 0xf, false); x = y < x ? y : x;
    y = (u32)__builtin_amdgcn_update_dpp((int)0xFFFFFFFF, (int)x, 0x114, 0xf, 0xf, false); x = y < x ? y : x;
    y = (u32)__builtin_amdgcn_update_dpp((int)0xFFFFFFFF, (int)x, 0x118, 0xf, 0xf, false); x = y < x ? y : x;
    y = (u32)__builtin_amdgcn_update_dpp((int)0xFFFFFFFF, (int)x, 0x142, 0xa, 0xf, false); x = y < x ? y : x;
    y = (u32)__builtin_amdgcn_update_dpp((int)0xFFFFFFFF, (int)x, 0x143, 0xc, 0xf, false); x = y < x ? y : x;
    return x;
}

// ---------------- exact sparse Prim on G' — single-LDS-hop steps ---------------
// Same pop semantics as before: key = rank(13)<<13 | vertex(13), min-key pop ==
// reference's (value, first-index) argmin. Per step: ONE dependent ds_read_b128
// (adj4[v]) + parallel row read of sMind -> straight-line PROC x4 -> two
// concurrent DPP min chains -> readlane. The entry u32 IS the pop key.
// sMind[v]: u16 best rank; 0x3FFF = empty, 0xFFFF = in-tree.
__global__ __launch_bounds__(256) void gprim_kernel(const uint4* __restrict__ adj4,
                                                    const u64* __restrict__ ovf,
                                                    const u32* __restrict__ adjG,
                                                    u32* __restrict__ seqv,
                                                    u32* __restrict__ ctr) {
    __shared__ uint4 sAdj4[8192];    // 128 KB, fixed 4-slot adjacency
    __shared__ u16 sMind[8192];      // 16 KB, row L = vertices {L, L+64, ...}
    const int t = threadIdx.x;
    for (int i = t; i < 8192; i += 256) sAdj4[i] = adj4[i];
    { u32* p = (u32*)sMind; for (int i = t; i < 4096; i += 256) p[i] = 0x3FFF3FFFu; }
    __syncthreads();
    if (t >= 64) return;                       // one wave runs the serial Prim
    const int lane = t;
    if (lane == 0) sMind[0] = 0xFFFFu;         // vertex 0 in tree
    u64 ins0 = (lane == 0) ? 1ull : 0ull, ins1 = 0ull;  // in-tree bits, my 128 verts
    u32 cmin = 0xFFFFFFFFu;
    u32 v = 0u, Lv = 0u;

#define PROC(e) do { \
        u32 _e = (e); \
        if (_e < 0x04000000u && (((_e ^ (u32)lane) & 63u) == 0u)) { \
            u32 _far = _e & 8191u, _rk = _e >> 13; \
            u32 _slot = _far >> 6; \
            u64 _w = (_slot & 64u) ? ins1 : ins0; \
            if (((_w >> (_slot & 63u)) & 1ull) == 0ull) { \
                if (_e < patch) patch = _e; \
                u32 _loc = ((u32)lane << 7) + _slot; \
                u16 _old = sMind[_loc]; \
                if ((u16)_rk < _old) sMind[_loc] = (u16)_rk; \
            } \
        } \
    } while (0)

    for (int step = 0; step < N - 1; ++step) {
        // ---- issue both LDS reads up front (independent) ----
        u32 rowPair = ((const u32*)sMind)[(Lv << 6) + (u32)lane];
        uint4 A = sAdj4[v];
        u32 patch = 0xFFFFFFFFu;
        PROC(A.x); PROC(A.y); PROC(A.z);
        if (A.w == 0xFFFFFFFEu) {              // rare overflow: deg > 4
            u64 od = ovf[v];
            u32 o0 = (u32)od, dgv = (u32)(od >> 32);
            u32 q = 3;
            for (; q + 4 <= dgv; q += 4) {
                u32 e0 = adjG[o0 + q], e1 = adjG[o0 + q + 1];
                u32 e2 = adjG[o0 + q + 2], e3 = adjG[o0 + q + 3];
                PROC(e0); PROC(e1); PROC(e2); PROC(e3);
            }
            for (; q < dgv; q++) { u32 e = adjG[o0 + q]; PROC(e); }
        } else {
            PROC(A.w);
        }
        cmin = patch < cmin ? patch : cmin;    // non-owner lanes: keep exact
        // ---- row keys of owner row Lv (pre-insert state + patch covers rest) --
        u32 m0 = rowPair & 0xFFFFu, m1 = rowPair >> 16;
        u32 s0 = ((u32)lane << 1), s1 = s0 + 1u;
        u32 vslot = v >> 6;
        u32 k0 = (m0 < 0x3FFFu && s0 != vslot) ? ((m0 << 13) | (s0 << 6) | Lv) : 0xFFFFFFFFu;
        u32 k1 = (m1 < 0x3FFFu && s1 != vslot) ? ((m1 << 13) | (s1 << 6) | Lv) : 0xFFFFFFFFu;
        u32 rowMin = k0 < k1 ? k0 : k1;
        // ---- two concurrent DPP chains: R = row-Lv rescan, C = cached mins ----
        u32 R = dpp_min_u32(rowMin);
        u32 xc = ((u32)lane == Lv) ? patch : cmin;
        u32 C = dpp_min_u32(xc);
        u32 Rs = (u32)__builtin_amdgcn_readlane((int)R, 63);
        u32 Cs = (u32)__builtin_amdgcn_readlane((int)C, 63);
        u32 g = Rs < Cs ? Rs : Cs;
        if ((u32)lane == Lv) cmin = Rs < patch ? Rs : patch;  // restore exactness
        if (g >= (0x3FFFu << 13)) { if (lane == 0) atomicOr(&ctr[2], 2u); break; }
        if (lane == 0) seqv[step] = g;
        // ---- mark popped vertex in tree ----
        v = g & 8191u; Lv = v & 63u;
        if ((u32)lane == Lv) {
            u32 nslot = v >> 6;
            if (nslot < 64u) ins0 |= 1ull << nslot; else ins1 |= 1ull << (nslot - 64u);
            sMind[(Lv << 7) + nslot] = 0xFFFFu;
        }
    }
#undef PROC
}

// ---------------- gather: deaths = sqrt(d2 of popped rank) ---------------------
__global__ void gather_kernel(const u32* __restrict__ seqv,
                              const u32* __restrict__ sortedWB,
                              float* __restrict__ out) {
    int s = blockIdx.x * blockDim.x + threadIdx.x;
    if (s < N - 1) {
        u32 p = seqv[s];
        u32 rk = p >> 13;
        out[2 * s + 1] = sqrtf(__uint_as_float(sortedWB[rk]));
    }
}

extern "C" void kernel_launch(void* const* d_in, const int* in_sizes, int n_in,
                              void* d_out, int out_size, void* d_ws, size_t ws_size,
                              hipStream_t stream) {
    const float* x = (const float*)d_in[0];
    float* out = (float*)d_out;

    char* ws = (char*)d_ws;
    size_t o = 0;
    u64* bestR    = (u64*)(ws + o); o += 8192 * 8;            // 64 KB
    u64* bestC    = (u64*)(ws + o); o += 8192 * 8;            // 64 KB
    u64* mstKeys  = (u64*)(ws + o); o += 8192 * 8;            // 64 KB
    u64* edges    = (u64*)(ws + o); o += (size_t)CAP_E * 8;   // 16 MB
    float* norms  = (float*)(ws + o); o += 8192 * 4;
    u32* sortedWB = (u32*)(ws + o); o += 8192 * 4;
    u32* deg      = (u32*)(ws + o); o += 8192 * 4;
    u32* offs     = (u32*)(ws + o); o += 8200 * 4;
    u32* cur      = (u32*)(ws + o); o += 8192 * 4;
    u32* seqv     = (u32*)(ws + o); o += 8192 * 4;
    u32* adj      = (u32*)(ws + o); o += (size_t)CAP_E * 2 * 4; // 16 MB
    uint4* adj4   = (uint4*)(ws + o); o += 8192 * 16;         // 128 KB
    u64* ovf      = (u64*)(ws + o); o += 8192 * 8;            // 64 KB
    u16* comp16   = (u16*)(ws + o); o += 8192 * 2;
    u32* ctr      = (u32*)(ws + o); o += 256;
    // total ~33 MB << 256 MiB

    zero_out_kernel<<<(out_size + 255) / 256, 256, 0, stream>>>(out, out_size);
    norms_kernel<<<32, 256, 0, stream>>>(x, norms);
    init_kernel<<<32, 256, 0, stream>>>(bestR, bestC, comp16, deg, ctr);

    for (int r = 0; r < 13; r++) {
        scan_fused<<<dim3(128, 128), 256, 0, stream>>>(x, norms, comp16, bestR, ctr);
        fold_kernel<<<32, 256, 0, stream>>>(bestR, bestC, comp16, ctr);
        merge_kernel<<<1, 1024, 0, stream>>>(comp16, bestC, mstKeys, ctr);
    }

    sort_kernel<<<1, 1024, 0, stream>>>(mstKeys, sortedWB, ctr);
    collect_kernel<<<dim3(128, 128), 256, 0, stream>>>(x, norms, sortedWB, edges, ctr);
    degcnt_kernel<<<512, 256, 0, stream>>>(edges, deg, ctr);
    offs_kernel<<<1, 1024, 0, stream>>>(deg, offs, cur);
    fill_kernel<<<512, 256, 0, stream>>>(edges, cur, adj, ctr);
    adj4_kernel<<<32, 256, 0, stream>>>(offs, adj, adj4, ovf);
    gprim_kernel<<<1, 256, 0, stream>>>(adj4, ovf, adj, seqv, ctr);
    gather_kernel<<<32, 256, 0, stream>>>(seqv, sortedWB, out);
}

// Round 3
// 6133.619 us; speedup vs baseline: 1.6533x; 1.0200x over previous
//
#include <hip/hip_runtime.h>
#include <math.h>

#define N 8192
#define DIM 64
#define CAP_E 2000000

typedef unsigned long long u64;
typedef unsigned int u32;
typedef unsigned short u16;

// ---------------- zero the output buffer (births stay 0) -----------------------
__global__ void zero_out_kernel(float* __restrict__ out, int n) {
    int i = blockIdx.x * blockDim.x + threadIdx.x;
    if (i < n) out[i] = 0.0f;
}

// ---------------- canonical norms: ni = sum fmaf(x_k, x_k) ascending k ---------
__global__ __launch_bounds__(256) void norms_kernel(const float* __restrict__ x,
                                                    float* __restrict__ norms) {
    int i = blockIdx.x * blockDim.x + threadIdx.x;
    const float* row = x + (size_t)i * DIM;
    float acc = 0.f;
    #pragma unroll
    for (int k = 0; k < DIM; k++) { float v = row[k]; acc = __builtin_fmaf(v, v, acc); }
    norms[i] = acc;
}

// ---------------- canonical tile machinery (shared by scan & collect) ----------
// [64][65] padding: write-phase bank conflicts drop 4-way -> 2-way (free).
__device__ inline void stage_tiles(const float* __restrict__ x, int bi, int bj, int t,
                                   float (*As)[65], float (*Bs)[65]) {
    int r = t >> 2, c0 = (t & 3) * 16;
    const float4* pa = (const float4*)(x + (size_t)(bi * 64 + r) * DIM + c0);
    const float4* pb = (const float4*)(x + (size_t)(bj * 64 + r) * DIM + c0);
    #pragma unroll
    for (int q = 0; q < 4; q++) {
        float4 a = pa[q], b = pb[q];
        int c = c0 + q * 4;
        As[c + 0][r] = a.x; As[c + 1][r] = a.y; As[c + 2][r] = a.z; As[c + 3][r] = a.w;
        Bs[c + 0][r] = b.x; Bs[c + 1][r] = b.y; Bs[c + 2][r] = b.z; Bs[c + 3][r] = b.w;
    }
}

__device__ inline void tile_d2(const float (*As)[65], const float (*Bs)[65],
                               const float ni[4], const float nj[4],
                               int tx, int ty, u32 d2b[4][4]) {
    float acc[4][4] = {};
    #pragma unroll 4
    for (int k = 0; k < 64; k++) {
        float av[4], bv[4];
        #pragma unroll
        for (int r = 0; r < 4; r++) av[r] = As[k][ty * 4 + r];
        #pragma unroll
        for (int c = 0; c < 4; c++) bv[c] = Bs[k][tx * 4 + c];
        #pragma unroll
        for (int r = 0; r < 4; r++)
            #pragma unroll
            for (int c = 0; c < 4; c++)
                acc[r][c] = __builtin_fmaf(av[r], bv[c], acc[r][c]);
    }
    #pragma unroll
    for (int r = 0; r < 4; r++)
        #pragma unroll
        for (int c = 0; c < 4; c++) {
            float d2 = __builtin_fmaf(-2.0f, acc[r][c], ni[r] + nj[c]);
            d2 = d2 < 0.f ? 0.f : d2;
            d2b[r][c] = __float_as_uint(d2);
        }
}

// ---------------- init ---------------------------------------------------------
// ctr[0]=mstCount ctr[1]=done ctr[2]=flag ctr[3]=edgeCount ctr[4]=gprimDone
__global__ void init_kernel(u64* bestR, u64* bestC, u16* comp16, u32* deg, u32* ctr) {
    int i = blockIdx.x * blockDim.x + threadIdx.x;
    if (i < 8192) { bestR[i] = ~0ull; bestC[i] = ~0ull; comp16[i] = (u16)i; deg[i] = 0; }
    if (i < 8) ctr[i] = 0;
}

// ---------------- Boruvka fused scan: recompute tile + per-row best ------------
__global__ __launch_bounds__(256) void scan_fused(const float* __restrict__ x,
                                                  const float* __restrict__ norms,
                                                  const u16* __restrict__ comp16,
                                                  u64* __restrict__ bestR,
                                                  const u32* __restrict__ ctr) {
    if (ctr[1]) return;
    int bi = blockIdx.y, bj = blockIdx.x;
    if (bj < bi) return;
    __shared__ float As[64][65], Bs[64][65];
    __shared__ u16 rc[64], cc[64];
    __shared__ u64 rowBest[64], colBest[64];
    int t = threadIdx.x;
    stage_tiles(x, bi, bj, t, As, Bs);
    if (t < 64) {
        rc[t] = comp16[bi * 64 + t];
        cc[t] = comp16[bj * 64 + t];
        rowBest[t] = ~0ull; colBest[t] = ~0ull;
    }
    __syncthreads();
    int tx = t & 15, ty = t >> 4;
    float ni[4], nj[4];
    #pragma unroll
    for (int r = 0; r < 4; r++) ni[r] = norms[bi * 64 + ty * 4 + r];
    #pragma unroll
    for (int c = 0; c < 4; c++) nj[c] = norms[bj * 64 + tx * 4 + c];
    u32 d2b[4][4];
    tile_d2(As, Bs, ni, nj, tx, ty, d2b);

    #pragma unroll
    for (int r = 0; r < 4; r++) {
        u16 rcv = rc[ty * 4 + r];
        int gi = bi * 64 + ty * 4 + r;
        u64 best = ~0ull;
        #pragma unroll
        for (int c = 0; c < 4; c++) {
            if (cc[tx * 4 + c] != rcv) {
                int gj = bj * 64 + tx * 4 + c;
                u32 lo = gi < gj ? (u32)gi : (u32)gj;
                u32 hi = gi < gj ? (u32)gj : (u32)gi;
                u64 key = ((u64)d2b[r][c] << 26) | ((u64)lo << 13) | hi;
                if (key < best) best = key;
            }
        }
        if (best != ~0ull) atomicMin(&rowBest[ty * 4 + r], best);
    }
    #pragma unroll
    for (int c = 0; c < 4; c++) {
        u16 ccv = cc[tx * 4 + c];
        int gj = bj * 64 + tx * 4 + c;
        u64 best = ~0ull;
        #pragma unroll
        for (int r = 0; r < 4; r++) {
            if (rc[ty * 4 + r] != ccv) {
                int gi = bi * 64 + ty * 4 + r;
                u32 lo = gi < gj ? (u32)gi : (u32)gj;
                u32 hi = gi < gj ? (u32)gj : (u32)gi;
                u64 key = ((u64)d2b[r][c] << 26) | ((u64)lo << 13) | hi;
                if (key < best) best = key;
            }
        }
        if (best != ~0ull) atomicMin(&colBest[tx * 4 + c], best);
    }
    __syncthreads();
    if (t < 64) {
        if (rowBest[t] != ~0ull) atomicMin(&bestR[bi * 64 + t], rowBest[t]);
        if (colBest[t] != ~0ull) atomicMin(&bestR[bj * 64 + t], colBest[t]);
    }
}

// ---------------- fold rows -> components --------------------------------------
__global__ void fold_kernel(u64* bestR, u64* bestC, const u16* comp16, const u32* ctr) {
    if (ctr[1]) return;
    int i = blockIdx.x * blockDim.x + threadIdx.x;
    if (i < 8192) {
        u64 k = bestR[i];
        if (k != ~0ull) { atomicMin(&bestC[comp16[i]], k); bestR[i] = ~0ull; }
    }
}

// ---------------- Boruvka merge ------------------------------------------------
__global__ __launch_bounds__(1024) void merge_kernel(u16* comp16, u64* bestC,
                                                     u64* mstKeys, u32* ctr) {
    __shared__ u16 ping[8192], pong[8192];
    __shared__ unsigned char act[8192];
    __shared__ u32 cnt_s;
    if (ctr[1]) return;
    int t = threadIdx.x;
    if (t == 0) cnt_s = 0;
    for (int c = t; c < 8192; c += 1024) {
        u64 key = bestC[c];
        u16 par = (u16)c;
        if (key != ~0ull) {
            u32 a = (u32)(key >> 13) & 8191u, b = (u32)key & 8191u;
            u16 ca = comp16[a];
            u16 cv = (ca == (u16)c) ? comp16[b] : ca;
            u64 k2 = bestC[cv];
            bool mutual = false;
            if (k2 != ~0ull) {
                u32 a2 = (u32)(k2 >> 13) & 8191u, b2 = (u32)k2 & 8191u;
                u16 ca2 = comp16[a2];
                u16 cv2 = (ca2 == cv) ? comp16[b2] : ca2;
                mutual = (cv2 == (u16)c);
            }
            par = cv;
            if (mutual && (u32)c < (u32)cv) par = (u16)c;
            bool add = (!mutual) || ((u32)c < (u32)cv);
            if (add) {
                u32 idx = atomicAdd(&ctr[0], 1u);
                if (idx < 8192u) mstKeys[idx] = key;
            }
        }
        ping[c] = par;
        act[c] = 0;
    }
    __syncthreads();
    for (int c = t; c < 8192; c += 1024) bestC[c] = ~0ull;   // reset for next round
    __syncthreads();
    for (int it = 0; it < 13; it++) {
        for (int c = t; c < 8192; c += 1024) pong[c] = ping[ping[c]];
        __syncthreads();
        for (int c = t; c < 8192; c += 1024) ping[c] = pong[c];
        __syncthreads();
    }
    for (int v = t; v < 8192; v += 1024) {
        u16 nc = ping[comp16[v]];
        comp16[v] = nc;
        act[nc] = 1;
    }
    __syncthreads();
    u32 local = 0;
    for (int c = t; c < 8192; c += 1024) local += act[c];
    atomicAdd(&cnt_s, local);
    __syncthreads();
    if (t == 0 && cnt_s == 1) ctr[1] = 1;
}

// ---------------- bitonic sort -> sorted d2 bit-patterns -----------------------
__global__ __launch_bounds__(1024) void sort_kernel(const u64* __restrict__ mstKeys,
                                                    u32* __restrict__ sortedWB,
                                                    const u32* __restrict__ ctr) {
    __shared__ u64 keys[8192];
    int t = threadIdx.x;
    u32 m = ctr[0]; if (m > 8191u) m = 8191u;
    for (int i = t; i < 8192; i += 1024) keys[i] = (i < (int)m) ? mstKeys[i] : ~0ull;
    __syncthreads();
    for (u32 k = 2; k <= 8192; k <<= 1)
        for (u32 j = k >> 1; j > 0; j >>= 1) {
            for (int i = t; i < 8192; i += 1024) {
                u32 ixj = (u32)i ^ j;
                if (ixj > (u32)i) {
                    u64 a = keys[i], b = keys[ixj];
                    bool up = ((i & k) == 0);
                    if ((a > b) == up) { keys[i] = b; keys[ixj] = a; }
                }
            }
            __syncthreads();
        }
    for (int i = t; i < 8192; i += 1024)
        sortedWB[i] = (i < 8191) ? (u32)(keys[i] >> 26) : 0xFFFFFFFFu;
}

// ---------------- collect G' = all pairs whose d2 equals an MST weight ---------
__global__ __launch_bounds__(256) void collect_kernel(const float* __restrict__ x,
                                                      const float* __restrict__ norms,
                                                      const u32* __restrict__ sortedWB,
                                                      u64* __restrict__ edges,
                                                      u32* __restrict__ ctr) {
    __shared__ float As[64][65], Bs[64][65];
    __shared__ u32 sw[8191];
    int bi = blockIdx.y, bj = blockIdx.x;
    if (bj < bi) return;
    int t = threadIdx.x;
    stage_tiles(x, bi, bj, t, As, Bs);
    for (int i = t; i < 8191; i += 256) sw[i] = sortedWB[i];
    __syncthreads();
    u32 wmin = sw[0], wmax = sw[8190];
    int tx = t & 15, ty = t >> 4;
    float ni[4], nj[4];
    #pragma unroll
    for (int r = 0; r < 4; r++) ni[r] = norms[bi * 64 + ty * 4 + r];
    #pragma unroll
    for (int c = 0; c < 4; c++) nj[c] = norms[bj * 64 + tx * 4 + c];
    u32 d2b[4][4];
    tile_d2(As, Bs, ni, nj, tx, ty, d2b);

    #pragma unroll
    for (int r = 0; r < 4; r++) {
        int gi = bi * 64 + ty * 4 + r;
        #pragma unroll
        for (int c = 0; c < 4; c++) {
            int gj = bj * 64 + tx * 4 + c;
            if (gj <= gi) continue;
            u32 wb = d2b[r][c];
            if (wb < wmin || wb > wmax) continue;
            int lo = 0, hi = 8190;
            while (lo < hi) { int mid = (lo + hi) >> 1; if (sw[mid] < wb) lo = mid + 1; else hi = mid; }
            if (sw[lo] == wb) {
                u32 idx = atomicAdd(&ctr[3], 1u);
                if (idx < CAP_E)
                    edges[idx] = ((u64)(u32)lo << 26) | ((u64)(u32)gi << 13) | (u32)gj;
                else
                    atomicOr(&ctr[2], 16u);
            }
        }
    }
}

// ---------------- degree count -------------------------------------------------
__global__ void degcnt_kernel(const u64* __restrict__ edges, u32* __restrict__ deg,
                              const u32* __restrict__ ctr) {
    u32 m = ctr[3]; if (m > CAP_E) m = CAP_E;
    for (u32 idx = blockIdx.x * 256u + threadIdx.x; idx < m; idx += gridDim.x * 256u) {
        u64 e = edges[idx];
        atomicAdd(&deg[(u32)(e >> 13) & 8191u], 1u);
        atomicAdd(&deg[(u32)e & 8191u], 1u);
    }
}

// ---------------- prefix sum: offs[8193] + cur ---------------------------------
__global__ __launch_bounds__(1024) void offs_kernel(const u32* __restrict__ deg,
                                                    u32* __restrict__ offs,
                                                    u32* __restrict__ cur) {
    __shared__ u32 partial[1024];
    int t = threadIdx.x;
    u32 loc[8], s = 0;
    #pragma unroll
    for (int e = 0; e < 8; e++) { loc[e] = deg[t * 8 + e]; s += loc[e]; }
    partial[t] = s;
    __syncthreads();
    for (int d = 1; d < 1024; d <<= 1) {
        u32 v = (t >= d) ? partial[t - d] : 0;
        __syncthreads();
        partial[t] += v;
        __syncthreads();
    }
    u32 run = t ? partial[t - 1] : 0;
    #pragma unroll
    for (int e = 0; e < 8; e++) { offs[t * 8 + e] = run; cur[t * 8 + e] = run; run += loc[e]; }
    if (t == 1023) offs[8192] = run;
}

// ---------------- fill adjacency: entry = rank(13)<<13 | far(13) ---------------
__global__ void fill_kernel(const u64* __restrict__ edges, u32* __restrict__ cur,
                            u32* __restrict__ adj, const u32* __restrict__ ctr) {
    u32 m = ctr[3]; if (m > CAP_E) m = CAP_E;
    for (u32 idx = blockIdx.x * 256u + threadIdx.x; idx < m; idx += gridDim.x * 256u) {
        u64 e = edges[idx];
        u32 rk = (u32)(e >> 26) & 8191u;
        u32 i = (u32)(e >> 13) & 8191u, j = (u32)e & 8191u;
        u32 p1 = atomicAdd(&cur[i], 1u); adj[p1] = (rk << 13) | j;
        u32 p2 = atomicAdd(&cur[j], 1u); adj[p2] = (rk << 13) | i;
    }
}

// ---------------- pack adjacency: 4 inline slots + rare overflow ---------------
// adj4[v] = {e0,e1,e2,e3} padded with 0xFFFFFFFF; deg>4 -> 3 inline + marker
// 0xFFFFFFFE in .w, extras read from CSR (ovf[v] = dg<<32 | o0) on demand.
// Valid entries are < 2^26, so "pred = e < 0x04000000" filters pad/marker.
__global__ __launch_bounds__(256) void adj4_kernel(const u32* __restrict__ offs,
                                                   const u32* __restrict__ adjG,
                                                   uint4* __restrict__ adj4,
                                                   u64* __restrict__ ovf) {
    int v = blockIdx.x * 256 + threadIdx.x;
    if (v >= N) return;
    u32 o0 = offs[v], o1 = offs[v + 1], dg = o1 - o0;
    u32 e[4] = {0xFFFFFFFFu, 0xFFFFFFFFu, 0xFFFFFFFFu, 0xFFFFFFFFu};
    u32 nin = dg <= 4u ? dg : 3u;
    for (u32 q = 0; q < nin; q++) e[q] = adjG[o0 + q];
    if (dg > 4u) e[3] = 0xFFFFFFFEu;
    adj4[v] = make_uint4(e[0], e[1], e[2], e[3]);
    ovf[v] = ((u64)dg << 32) | o0;
}

// ---------------- wave64 min-reduce via DPP (result valid in lane 63) ----------
__device__ __forceinline__ u32 dpp_min_u32(u32 x) {
    u32 y;
    y = (u32)__builtin_amdgcn_update_dpp((int)0xFFFFFFFF, (int)x, 0x111, 0xf, 0xf, false); x = y < x ? y : x;
    y = (u32)__builtin_amdgcn_update_dpp((int)0xFFFFFFFF, (int)x, 0x112, 0xf, 0xf, false); x = y < x ? y : x;
    y = (u32)__builtin_amdgcn_update_dpp((int)0xFFFFFFFF, (int)x, 0x114, 0xf, 0xf, false); x = y < x ? y : x;
    y = (u32)__builtin_amdgcn_update_dpp((int)0xFFFFFFFF, (int)x, 0x118, 0xf, 0xf, false); x = y < x ? y : x;
    y = (u32)__builtin_amdgcn_update_dpp((int)0xFFFFFFFF, (int)x, 0x142, 0xa, 0xf, false); x = y < x ? y : x;
    y = (u32)__builtin_amdgcn_update_dpp((int)0xFFFFFFFF, (int)x, 0x143, 0xc, 0xf, false); x = y < x ? y : x;
    return x;
}

// ---------------- exact sparse Prim on G' — single-LDS-hop steps ---------------
// Block 0: identical serial Prim wave to r2 (same pop semantics, bit-identical
// output). Blocks 1..192: DVFS keep-alive spinners, each on its own CU, light
// FMA spin + device-scope poll of ctr[4]; they never block the Prim wave and
// exit ~1us after it sets the flag. Tests the "gprim runs at idle clock"
// hypothesis without touching the algorithm.
__global__ __launch_bounds__(256) void gprim_kernel(const uint4* __restrict__ adj4,
                                                    const u64* __restrict__ ovf,
                                                    const u32* __restrict__ adjG,
                                                    u32* __restrict__ seqv,
                                                    u32* __restrict__ ctr) {
    if (blockIdx.x != 0) {
        // ---- clock keep-alive spinner ----
        __shared__ u32 sdone;
        if (threadIdx.x == 0) sdone = 0;
        __syncthreads();
        float c0 = 0.f, c1 = 0.f, c2 = 0.f, c3 = 0.f;
        float a = 1.0f + (float)(threadIdx.x & 31) * 1e-7f;
        for (u32 it = 0; it < 500000u; ++it) {
            #pragma unroll
            for (int k = 0; k < 8; ++k) {
                c0 = __builtin_fmaf(a, 1.0000001f, c0);
                c1 = __builtin_fmaf(a, 1.0000002f, c1);
                c2 = __builtin_fmaf(a, 1.0000003f, c2);
                c3 = __builtin_fmaf(a, 1.0000004f, c3);
            }
            if ((it & 63u) == 0u) {
                if (threadIdx.x == 0 && atomicAdd(&ctr[4], 0u) != 0u) sdone = 1u;
                __syncthreads();
                if (sdone) break;
            }
        }
        asm volatile("" :: "v"(c0), "v"(c1), "v"(c2), "v"(c3));
        return;
    }

    __shared__ uint4 sAdj4[8192];    // 128 KB, fixed 4-slot adjacency
    __shared__ u16 sMind[8192];      // 16 KB, row L = vertices {L, L+64, ...}
    const int t = threadIdx.x;
    for (int i = t; i < 8192; i += 256) sAdj4[i] = adj4[i];
    { u32* p = (u32*)sMind; for (int i = t; i < 4096; i += 256) p[i] = 0x3FFF3FFFu; }
    __syncthreads();
    if (t >= 64) return;                       // one wave runs the serial Prim
    __builtin_amdgcn_s_setprio(3);
    const int lane = t;
    if (lane == 0) sMind[0] = 0xFFFFu;         // vertex 0 in tree
    u64 ins0 = (lane == 0) ? 1ull : 0ull, ins1 = 0ull;  // in-tree bits, my 128 verts
    u32 cmin = 0xFFFFFFFFu;
    u32 v = 0u, Lv = 0u;

#define PROC(e) do { \
        u32 _e = (e); \
        if (_e < 0x04000000u && (((_e ^ (u32)lane) & 63u) == 0u)) { \
            u32 _far = _e & 8191u, _rk = _e >> 13; \
            u32 _slot = _far >> 6; \
            u64 _w = (_slot & 64u) ? ins1 : ins0; \
            if (((_w >> (_slot & 63u)) & 1ull) == 0ull) { \
                if (_e < patch) patch = _e; \
                u32 _loc = ((u32)lane << 7) + _slot; \
                u16 _old = sMind[_loc]; \
                if ((u16)_rk < _old) sMind[_loc] = (u16)_rk; \
            } \
        } \
    } while (0)

    for (int step = 0; step < N - 1; ++step) {
        // ---- issue both LDS reads up front (independent) ----
        u32 rowPair = ((const u32*)sMind)[(Lv << 6) + (u32)lane];
        uint4 A = sAdj4[v];
        u32 patch = 0xFFFFFFFFu;
        PROC(A.x); PROC(A.y); PROC(A.z);
        if (A.w == 0xFFFFFFFEu) {              // rare overflow: deg > 4
            u64 od = ovf[v];
            u32 o0 = (u32)od, dgv = (u32)(od >> 32);
            u32 q = 3;
            for (; q + 4 <= dgv; q += 4) {
                u32 e0 = adjG[o0 + q], e1 = adjG[o0 + q + 1];
                u32 e2 = adjG[o0 + q + 2], e3 = adjG[o0 + q + 3];
                PROC(e0); PROC(e1); PROC(e2); PROC(e3);
            }
            for (; q < dgv; q++) { u32 e = adjG[o0 + q]; PROC(e); }
        } else {
            PROC(A.w);
        }
        cmin = patch < cmin ? patch : cmin;    // non-owner lanes: keep exact
        // ---- row keys of owner row Lv (pre-insert state + patch covers rest) --
        u32 m0 = rowPair & 0xFFFFu, m1 = rowPair >> 16;
        u32 s0 = ((u32)lane << 1), s1 = s0 + 1u;
        u32 vslot = v >> 6;
        u32 k0 = (m0 < 0x3FFFu && s0 != vslot) ? ((m0 << 13) | (s0 << 6) | Lv) : 0xFFFFFFFFu;
        u32 k1 = (m1 < 0x3FFFu && s1 != vslot) ? ((m1 << 13) | (s1 << 6) | Lv) : 0xFFFFFFFFu;
        u32 rowMin = k0 < k1 ? k0 : k1;
        // ---- two concurrent DPP chains: R = row-Lv rescan, C = cached mins ----
        u32 R = dpp_min_u32(rowMin);
        u32 xc = ((u32)lane == Lv) ? patch : cmin;
        u32 C = dpp_min_u32(xc);
        u32 Rs = (u32)__builtin_amdgcn_readlane((int)R, 63);
        u32 Cs = (u32)__builtin_amdgcn_readlane((int)C, 63);
        u32 g = Rs < Cs ? Rs : Cs;
        if ((u32)lane == Lv) cmin = Rs < patch ? Rs : patch;  // restore exactness
        if (g >= (0x3FFFu << 13)) { if (lane == 0) atomicOr(&ctr[2], 2u); break; }
        if (lane == 0) seqv[step] = g;
        // ---- mark popped vertex in tree ----
        v = g & 8191u; Lv = v & 63u;
        if ((u32)lane == Lv) {
            u32 nslot = v >> 6;
            if (nslot < 64u) ins0 |= 1ull << nslot; else ins1 |= 1ull << (nslot - 64u);
            sMind[(Lv << 7) + nslot] = 0xFFFFu;
        }
    }
#undef PROC
    if (lane == 0) atomicOr(&ctr[4], 1u);      // release the spinners
}

// ---------------- gather: deaths = sqrt(d2 of popped rank) ---------------------
__global__ void gather_kernel(const u32* __restrict__ seqv,
                              const u32* __restrict__ sortedWB,
                              float* __restrict__ out) {
    int s = blockIdx.x * blockDim.x + threadIdx.x;
    if (s < N - 1) {
        u32 p = seqv[s];
        u32 rk = p >> 13;
        out[2 * s + 1] = sqrtf(__uint_as_float(sortedWB[rk]));
    }
}

extern "C" void kernel_launch(void* const* d_in, const int* in_sizes, int n_in,
                              void* d_out, int out_size, void* d_ws, size_t ws_size,
                              hipStream_t stream) {
    const float* x = (const float*)d_in[0];
    float* out = (float*)d_out;

    char* ws = (char*)d_ws;
    size_t o = 0;
    u64* bestR    = (u64*)(ws + o); o += 8192 * 8;            // 64 KB
    u64* bestC    = (u64*)(ws + o); o += 8192 * 8;            // 64 KB
    u64* mstKeys  = (u64*)(ws + o); o += 8192 * 8;            // 64 KB
    u64* edges    = (u64*)(ws + o); o += (size_t)CAP_E * 8;   // 16 MB
    float* norms  = (float*)(ws + o); o += 8192 * 4;
    u32* sortedWB = (u32*)(ws + o); o += 8192 * 4;
    u32* deg      = (u32*)(ws + o); o += 8192 * 4;
    u32* offs     = (u32*)(ws + o); o += 8200 * 4;
    u32* cur      = (u32*)(ws + o); o += 8192 * 4;
    u32* seqv     = (u32*)(ws + o); o += 8192 * 4;
    u32* adj      = (u32*)(ws + o); o += (size_t)CAP_E * 2 * 4; // 16 MB
    uint4* adj4   = (uint4*)(ws + o); o += 8192 * 16;         // 128 KB
    u64* ovf      = (u64*)(ws + o); o += 8192 * 8;            // 64 KB
    u16* comp16   = (u16*)(ws + o); o += 8192 * 2;
    u32* ctr      = (u32*)(ws + o); o += 256;
    // total ~33 MB << 256 MiB

    zero_out_kernel<<<(out_size + 255) / 256, 256, 0, stream>>>(out, out_size);
    norms_kernel<<<32, 256, 0, stream>>>(x, norms);
    init_kernel<<<32, 256, 0, stream>>>(bestR, bestC, comp16, deg, ctr);

    for (int r = 0; r < 13; r++) {
        scan_fused<<<dim3(128, 128), 256, 0, stream>>>(x, norms, comp16, bestR, ctr);
        fold_kernel<<<32, 256, 0, stream>>>(bestR, bestC, comp16, ctr);
        merge_kernel<<<1, 1024, 0, stream>>>(comp16, bestC, mstKeys, ctr);
    }

    sort_kernel<<<1, 1024, 0, stream>>>(mstKeys, sortedWB, ctr);
    collect_kernel<<<dim3(128, 128), 256, 0, stream>>>(x, norms, sortedWB, edges, ctr);
    degcnt_kernel<<<512, 256, 0, stream>>>(edges, deg, ctr);
    offs_kernel<<<1, 1024, 0, stream>>>(deg, offs, cur);
    fill_kernel<<<512, 256, 0, stream>>>(edges, cur, adj, ctr);
    adj4_kernel<<<32, 256, 0, stream>>>(offs, adj, adj4, ovf);
    gprim_kernel<<<193, 256, 0, stream>>>(adj4, ovf, adj, seqv, ctr);
    gather_kernel<<<32, 256, 0, stream>>>(seqv, sortedWB, out);
}

// Round 4
// 5983.322 us; speedup vs baseline: 1.6948x; 1.0251x over previous
//
#include <hip/hip_runtime.h>
#include <math.h>

#define N 8192
#define DIM 64
#define CAP_E 2000000
#define INLINE_V 8064   // vertices with LDS-inline adj4; tail reads global (L2)

typedef unsigned long long u64;
typedef unsigned int u32;
typedef unsigned short u16;

// ---------------- zero the output buffer (births stay 0) -----------------------
__global__ void zero_out_kernel(float* __restrict__ out, int n) {
    int i = blockIdx.x * blockDim.x + threadIdx.x;
    if (i < n) out[i] = 0.0f;
}

// ---------------- canonical norms: ni = sum fmaf(x_k, x_k) ascending k ---------
__global__ __launch_bounds__(256) void norms_kernel(const float* __restrict__ x,
                                                    float* __restrict__ norms) {
    int i = blockIdx.x * blockDim.x + threadIdx.x;
    const float* row = x + (size_t)i * DIM;
    float acc = 0.f;
    #pragma unroll
    for (int k = 0; k < DIM; k++) { float v = row[k]; acc = __builtin_fmaf(v, v, acc); }
    norms[i] = acc;
}

// ---------------- canonical tile machinery (shared by scan & collect) ----------
// [64][65] padding: write-phase bank conflicts drop 4-way -> 2-way (free).
__device__ inline void stage_tiles(const float* __restrict__ x, int bi, int bj, int t,
                                   float (*As)[65], float (*Bs)[65]) {
    int r = t >> 2, c0 = (t & 3) * 16;
    const float4* pa = (const float4*)(x + (size_t)(bi * 64 + r) * DIM + c0);
    const float4* pb = (const float4*)(x + (size_t)(bj * 64 + r) * DIM + c0);
    #pragma unroll
    for (int q = 0; q < 4; q++) {
        float4 a = pa[q], b = pb[q];
        int c = c0 + q * 4;
        As[c + 0][r] = a.x; As[c + 1][r] = a.y; As[c + 2][r] = a.z; As[c + 3][r] = a.w;
        Bs[c + 0][r] = b.x; Bs[c + 1][r] = b.y; Bs[c + 2][r] = b.z; Bs[c + 3][r] = b.w;
    }
}

__device__ inline void tile_d2(const float (*As)[65], const float (*Bs)[65],
                               const float ni[4], const float nj[4],
                               int tx, int ty, u32 d2b[4][4]) {
    float acc[4][4] = {};
    #pragma unroll 4
    for (int k = 0; k < 64; k++) {
        float av[4], bv[4];
        #pragma unroll
        for (int r = 0; r < 4; r++) av[r] = As[k][ty * 4 + r];
        #pragma unroll
        for (int c = 0; c < 4; c++) bv[c] = Bs[k][tx * 4 + c];
        #pragma unroll
        for (int r = 0; r < 4; r++)
            #pragma unroll
            for (int c = 0; c < 4; c++)
                acc[r][c] = __builtin_fmaf(av[r], bv[c], acc[r][c]);
    }
    #pragma unroll
    for (int r = 0; r < 4; r++)
        #pragma unroll
        for (int c = 0; c < 4; c++) {
            float d2 = __builtin_fmaf(-2.0f, acc[r][c], ni[r] + nj[c]);
            d2 = d2 < 0.f ? 0.f : d2;
            d2b[r][c] = __float_as_uint(d2);
        }
}

// ---------------- init ---------------------------------------------------------
// ctr[0]=mstCount ctr[1]=done ctr[2]=flag ctr[3]=edgeCount
__global__ void init_kernel(u64* bestR, u64* bestC, u16* comp16, u32* deg, u32* ctr) {
    int i = blockIdx.x * blockDim.x + threadIdx.x;
    if (i < 8192) { bestR[i] = ~0ull; bestC[i] = ~0ull; comp16[i] = (u16)i; deg[i] = 0; }
    if (i < 8) ctr[i] = 0;
}

// ---------------- Boruvka fused scan: recompute tile + per-row best ------------
__global__ __launch_bounds__(256) void scan_fused(const float* __restrict__ x,
                                                  const float* __restrict__ norms,
                                                  const u16* __restrict__ comp16,
                                                  u64* __restrict__ bestR,
                                                  const u32* __restrict__ ctr) {
    if (ctr[1]) return;
    int bi = blockIdx.y, bj = blockIdx.x;
    if (bj < bi) return;
    __shared__ float As[64][65], Bs[64][65];
    __shared__ u16 rc[64], cc[64];
    __shared__ u64 rowBest[64], colBest[64];
    int t = threadIdx.x;
    stage_tiles(x, bi, bj, t, As, Bs);
    if (t < 64) {
        rc[t] = comp16[bi * 64 + t];
        cc[t] = comp16[bj * 64 + t];
        rowBest[t] = ~0ull; colBest[t] = ~0ull;
    }
    __syncthreads();
    int tx = t & 15, ty = t >> 4;
    float ni[4], nj[4];
    #pragma unroll
    for (int r = 0; r < 4; r++) ni[r] = norms[bi * 64 + ty * 4 + r];
    #pragma unroll
    for (int c = 0; c < 4; c++) nj[c] = norms[bj * 64 + tx * 4 + c];
    u32 d2b[4][4];
    tile_d2(As, Bs, ni, nj, tx, ty, d2b);

    #pragma unroll
    for (int r = 0; r < 4; r++) {
        u16 rcv = rc[ty * 4 + r];
        int gi = bi * 64 + ty * 4 + r;
        u64 best = ~0ull;
        #pragma unroll
        for (int c = 0; c < 4; c++) {
            if (cc[tx * 4 + c] != rcv) {
                int gj = bj * 64 + tx * 4 + c;
                u32 lo = gi < gj ? (u32)gi : (u32)gj;
                u32 hi = gi < gj ? (u32)gj : (u32)gi;
                u64 key = ((u64)d2b[r][c] << 26) | ((u64)lo << 13) | hi;
                if (key < best) best = key;
            }
        }
        if (best != ~0ull) atomicMin(&rowBest[ty * 4 + r], best);
    }
    #pragma unroll
    for (int c = 0; c < 4; c++) {
        u16 ccv = cc[tx * 4 + c];
        int gj = bj * 64 + tx * 4 + c;
        u64 best = ~0ull;
        #pragma unroll
        for (int r = 0; r < 4; r++) {
            if (rc[ty * 4 + r] != ccv) {
                int gi = bi * 64 + ty * 4 + r;
                u32 lo = gi < gj ? (u32)gi : (u32)gj;
                u32 hi = gi < gj ? (u32)gj : (u32)gi;
                u64 key = ((u64)d2b[r][c] << 26) | ((u64)lo << 13) | hi;
                if (key < best) best = key;
            }
        }
        if (best != ~0ull) atomicMin(&colBest[tx * 4 + c], best);
    }
    __syncthreads();
    if (t < 64) {
        if (rowBest[t] != ~0ull) atomicMin(&bestR[bi * 64 + t], rowBest[t]);
        if (colBest[t] != ~0ull) atomicMin(&bestR[bj * 64 + t], colBest[t]);
    }
}

// ---------------- fold rows -> components --------------------------------------
__global__ void fold_kernel(u64* bestR, u64* bestC, const u16* comp16, const u32* ctr) {
    if (ctr[1]) return;
    int i = blockIdx.x * blockDim.x + threadIdx.x;
    if (i < 8192) {
        u64 k = bestR[i];
        if (k != ~0ull) { atomicMin(&bestC[comp16[i]], k); bestR[i] = ~0ull; }
    }
}

// ---------------- Boruvka merge ------------------------------------------------
__global__ __launch_bounds__(1024) void merge_kernel(u16* comp16, u64* bestC,
                                                     u64* mstKeys, u32* ctr) {
    __shared__ u16 ping[8192], pong[8192];
    __shared__ unsigned char act[8192];
    __shared__ u32 cnt_s;
    if (ctr[1]) return;
    int t = threadIdx.x;
    if (t == 0) cnt_s = 0;
    for (int c = t; c < 8192; c += 1024) {
        u64 key = bestC[c];
        u16 par = (u16)c;
        if (key != ~0ull) {
            u32 a = (u32)(key >> 13) & 8191u, b = (u32)key & 8191u;
            u16 ca = comp16[a];
            u16 cv = (ca == (u16)c) ? comp16[b] : ca;
            u64 k2 = bestC[cv];
            bool mutual = false;
            if (k2 != ~0ull) {
                u32 a2 = (u32)(k2 >> 13) & 8191u, b2 = (u32)k2 & 8191u;
                u16 ca2 = comp16[a2];
                u16 cv2 = (ca2 == cv) ? comp16[b2] : ca2;
                mutual = (cv2 == (u16)c);
            }
            par = cv;
            if (mutual && (u32)c < (u32)cv) par = (u16)c;
            bool add = (!mutual) || ((u32)c < (u32)cv);
            if (add) {
                u32 idx = atomicAdd(&ctr[0], 1u);
                if (idx < 8192u) mstKeys[idx] = key;
            }
        }
        ping[c] = par;
        act[c] = 0;
    }
    __syncthreads();
    for (int c = t; c < 8192; c += 1024) bestC[c] = ~0ull;   // reset for next round
    __syncthreads();
    for (int it = 0; it < 13; it++) {
        for (int c = t; c < 8192; c += 1024) pong[c] = ping[ping[c]];
        __syncthreads();
        for (int c = t; c < 8192; c += 1024) ping[c] = pong[c];
        __syncthreads();
    }
    for (int v = t; v < 8192; v += 1024) {
        u16 nc = ping[comp16[v]];
        comp16[v] = nc;
        act[nc] = 1;
    }
    __syncthreads();
    u32 local = 0;
    for (int c = t; c < 8192; c += 1024) local += act[c];
    atomicAdd(&cnt_s, local);
    __syncthreads();
    if (t == 0 && cnt_s == 1) ctr[1] = 1;
}

// ---------------- bitonic sort -> sorted d2 bit-patterns -----------------------
__global__ __launch_bounds__(1024) void sort_kernel(const u64* __restrict__ mstKeys,
                                                    u32* __restrict__ sortedWB,
                                                    const u32* __restrict__ ctr) {
    __shared__ u64 keys[8192];
    int t = threadIdx.x;
    u32 m = ctr[0]; if (m > 8191u) m = 8191u;
    for (int i = t; i < 8192; i += 1024) keys[i] = (i < (int)m) ? mstKeys[i] : ~0ull;
    __syncthreads();
    for (u32 k = 2; k <= 8192; k <<= 1)
        for (u32 j = k >> 1; j > 0; j >>= 1) {
            for (int i = t; i < 8192; i += 1024) {
                u32 ixj = (u32)i ^ j;
                if (ixj > (u32)i) {
                    u64 a = keys[i], b = keys[ixj];
                    bool up = ((i & k) == 0);
                    if ((a > b) == up) { keys[i] = b; keys[ixj] = a; }
                }
            }
            __syncthreads();
        }
    for (int i = t; i < 8192; i += 1024)
        sortedWB[i] = (i < 8191) ? (u32)(keys[i] >> 26) : 0xFFFFFFFFu;
}

// ---------------- collect G' = all pairs whose d2 equals an MST weight ---------
__global__ __launch_bounds__(256) void collect_kernel(const float* __restrict__ x,
                                                      const float* __restrict__ norms,
                                                      const u32* __restrict__ sortedWB,
                                                      u64* __restrict__ edges,
                                                      u32* __restrict__ ctr) {
    __shared__ float As[64][65], Bs[64][65];
    __shared__ u32 sw[8191];
    int bi = blockIdx.y, bj = blockIdx.x;
    if (bj < bi) return;
    int t = threadIdx.x;
    stage_tiles(x, bi, bj, t, As, Bs);
    for (int i = t; i < 8191; i += 256) sw[i] = sortedWB[i];
    __syncthreads();
    u32 wmin = sw[0], wmax = sw[8190];
    int tx = t & 15, ty = t >> 4;
    float ni[4], nj[4];
    #pragma unroll
    for (int r = 0; r < 4; r++) ni[r] = norms[bi * 64 + ty * 4 + r];
    #pragma unroll
    for (int c = 0; c < 4; c++) nj[c] = norms[bj * 64 + tx * 4 + c];
    u32 d2b[4][4];
    tile_d2(As, Bs, ni, nj, tx, ty, d2b);

    #pragma unroll
    for (int r = 0; r < 4; r++) {
        int gi = bi * 64 + ty * 4 + r;
        #pragma unroll
        for (int c = 0; c < 4; c++) {
            int gj = bj * 64 + tx * 4 + c;
            if (gj <= gi) continue;
            u32 wb = d2b[r][c];
            if (wb < wmin || wb > wmax) continue;
            int lo = 0, hi = 8190;
            while (lo < hi) { int mid = (lo + hi) >> 1; if (sw[mid] < wb) lo = mid + 1; else hi = mid; }
            if (sw[lo] == wb) {
                u32 idx = atomicAdd(&ctr[3], 1u);
                if (idx < CAP_E)
                    edges[idx] = ((u64)(u32)lo << 26) | ((u64)(u32)gi << 13) | (u32)gj;
                else
                    atomicOr(&ctr[2], 16u);
            }
        }
    }
}

// ---------------- degree count -------------------------------------------------
__global__ void degcnt_kernel(const u64* __restrict__ edges, u32* __restrict__ deg,
                              const u32* __restrict__ ctr) {
    u32 m = ctr[3]; if (m > CAP_E) m = CAP_E;
    for (u32 idx = blockIdx.x * 256u + threadIdx.x; idx < m; idx += gridDim.x * 256u) {
        u64 e = edges[idx];
        atomicAdd(&deg[(u32)(e >> 13) & 8191u], 1u);
        atomicAdd(&deg[(u32)e & 8191u], 1u);
    }
}

// ---------------- prefix sum: offs[8193] + cur ---------------------------------
__global__ __launch_bounds__(1024) void offs_kernel(const u32* __restrict__ deg,
                                                    u32* __restrict__ offs,
                                                    u32* __restrict__ cur) {
    __shared__ u32 partial[1024];
    int t = threadIdx.x;
    u32 loc[8], s = 0;
    #pragma unroll
    for (int e = 0; e < 8; e++) { loc[e] = deg[t * 8 + e]; s += loc[e]; }
    partial[t] = s;
    __syncthreads();
    for (int d = 1; d < 1024; d <<= 1) {
        u32 v = (t >= d) ? partial[t - d] : 0;
        __syncthreads();
        partial[t] += v;
        __syncthreads();
    }
    u32 run = t ? partial[t - 1] : 0;
    #pragma unroll
    for (int e = 0; e < 8; e++) { offs[t * 8 + e] = run; cur[t * 8 + e] = run; run += loc[e]; }
    if (t == 1023) offs[8192] = run;
}

// ---------------- fill adjacency: entry = rank(13)<<13 | far(13) ---------------
__global__ void fill_kernel(const u64* __restrict__ edges, u32* __restrict__ cur,
                            u32* __restrict__ adj, const u32* __restrict__ ctr) {
    u32 m = ctr[3]; if (m > CAP_E) m = CAP_E;
    for (u32 idx = blockIdx.x * 256u + threadIdx.x; idx < m; idx += gridDim.x * 256u) {
        u64 e = edges[idx];
        u32 rk = (u32)(e >> 26) & 8191u;
        u32 i = (u32)(e >> 13) & 8191u, j = (u32)e & 8191u;
        u32 p1 = atomicAdd(&cur[i], 1u); adj[p1] = (rk << 13) | j;
        u32 p2 = atomicAdd(&cur[j], 1u); adj[p2] = (rk << 13) | i;
    }
}

// ---------------- pack adjacency: 4 inline slots + rare overflow ---------------
// adj4[v] = {e0,e1,e2,e3} padded with 0xFFFFFFFF; deg>4 -> 3 inline + marker
// 0xFFFFFFFE in .w, extras read from CSR (ovf[v] = dg<<32 | o0) on demand.
// Valid entries are < 2^26, so "pred = e < 0x04000000" filters pad/marker.
__global__ __launch_bounds__(256) void adj4_kernel(const u32* __restrict__ offs,
                                                   const u32* __restrict__ adjG,
                                                   uint4* __restrict__ adj4,
                                                   u64* __restrict__ ovf) {
    int v = blockIdx.x * 256 + threadIdx.x;
    if (v >= N) return;
    u32 o0 = offs[v], o1 = offs[v + 1], dg = o1 - o0;
    u32 e[4] = {0xFFFFFFFFu, 0xFFFFFFFFu, 0xFFFFFFFFu, 0xFFFFFFFFu};
    u32 nin = dg <= 4u ? dg : 3u;
    for (u32 q = 0; q < nin; q++) e[q] = adjG[o0 + q];
    if (dg > 4u) e[3] = 0xFFFFFFFEu;
    adj4[v] = make_uint4(e[0], e[1], e[2], e[3]);
    ovf[v] = ((u64)dg << 32) | o0;
}

// ---------------- wave64 min-reduce via DPP (result valid in lane 63) ----------
__device__ __forceinline__ u32 dpp_min_u32(u32 x) {
    u32 y;
    y = (u32)__builtin_amdgcn_update_dpp((int)0xFFFFFFFF, (int)x, 0x111, 0xf, 0xf, false); x = y < x ? y : x;
    y = (u32)__builtin_amdgcn_update_dpp((int)0xFFFFFFFF, (int)x, 0x112, 0xf, 0xf, false); x = y < x ? y : x;
    y = (u32)__builtin_amdgcn_update_dpp((int)0xFFFFFFFF, (int)x, 0x114, 0xf, 0xf, false); x = y < x ? y : x;
    y = (u32)__builtin_amdgcn_update_dpp((int)0xFFFFFFFF, (int)x, 0x118, 0xf, 0xf, false); x = y < x ? y : x;
    y = (u32)__builtin_amdgcn_update_dpp((int)0xFFFFFFFF, (int)x, 0x142, 0xa, 0xf, false); x = y < x ? y : x;
    y = (u32)__builtin_amdgcn_update_dpp((int)0xFFFFFFFF, (int)x, 0x143, 0xc, 0xf, false); x = y < x ? y : x;
    return x;
}

// ---------------- exact sparse Prim on G' — ds_min fire-and-forget -------------
// Same pop semantics: key = rank(13)<<13 | vertex(13), min-key pop == reference's
// (value, first-index) argmin. sMind32[v]: u32 best rank; 0x3FFF = empty,
// 0xFFFFFFFF = in-tree. Maintained via ds_min_u32 (atomicMin, result unused) --
// NO read latency on the critical path. Row rescan reads uint2/lane; inserts
// this step are covered by `patch`; the (slot != vslot) guard protects the
// sentinel race, so ordering of the rescan read vs the ds_mins is immaterial.
__global__ __launch_bounds__(256) void gprim_kernel(const uint4* __restrict__ adj4,
                                                    const u64* __restrict__ ovf,
                                                    const u32* __restrict__ adjG,
                                                    u32* __restrict__ seqv,
                                                    u32* __restrict__ ctr) {
    __shared__ uint4 sAdj4[INLINE_V];   // 129 KB inline adjacency (v < INLINE_V)
    __shared__ u32 sMind32[8192];       // 32 KB, row L = vertices {L, L+64, ...}
    const int t = threadIdx.x;
    for (int i = t; i < INLINE_V; i += 256) sAdj4[i] = adj4[i];
    for (int i = t; i < 8192; i += 256) sMind32[i] = 0x3FFFu;
    __syncthreads();
    if (t >= 64) return;                       // one wave runs the serial Prim
    __builtin_amdgcn_s_setprio(3);
    const int lane = t;
    if (lane == 0) sMind32[0] = 0xFFFFFFFFu;   // vertex 0 in tree
    u64 ins0 = (lane == 0) ? 1ull : 0ull, ins1 = 0ull;  // in-tree bits, my 128 verts
    u32 cmin = 0xFFFFFFFFu;
    u32 v = 0u, Lv = 0u;

#define PROC(e) do { \
        u32 _e = (e); \
        u32 _far = _e & 8191u; \
        u32 _slot = _far >> 6; \
        u64 _w = (_slot & 64u) ? ins1 : ins0; \
        bool _ok = (_e < 0x04000000u) && (((_far ^ (u32)lane) & 63u) == 0u) \
                   && (((_w >> (_slot & 63u)) & 1ull) == 0ull); \
        patch = (_ok && _e < patch) ? _e : patch; \
        if (_ok) atomicMin(&sMind32[((u32)lane << 7) + _slot], _e >> 13); \
    } while (0)

    for (int step = 0; step < N - 1; ++step) {
        // ---- issue rescan-row read + adjacency read up front (independent) ----
        uint2 rp = *(const uint2*)&sMind32[(Lv << 7) + 2u * (u32)lane];
        uint4 A = (v < (u32)INLINE_V) ? sAdj4[v] : adj4[v];
        u32 patch = 0xFFFFFFFFu;
        PROC(A.x); PROC(A.y); PROC(A.z);
        if (A.w == 0xFFFFFFFEu) {              // rare overflow: deg > 4
            u64 od = ovf[v];
            u32 o0 = (u32)od, dgv = (u32)(od >> 32);
            u32 q = 3;
            for (; q + 4 <= dgv; q += 4) {
                u32 e0 = adjG[o0 + q], e1 = adjG[o0 + q + 1];
                u32 e2 = adjG[o0 + q + 2], e3 = adjG[o0 + q + 3];
                PROC(e0); PROC(e1); PROC(e2); PROC(e3);
            }
            for (; q < dgv; q++) { u32 e = adjG[o0 + q]; PROC(e); }
        } else {
            PROC(A.w);
        }
        cmin = patch < cmin ? patch : cmin;    // non-owner lanes: keep exact
        // ---- row keys of rescan row Lv (patch covers this step's inserts) ----
        u32 m0 = rp.x, m1 = rp.y;
        u32 s0 = ((u32)lane << 1), s1 = s0 | 1u;
        u32 vslot = v >> 6;
        u32 k0 = (m0 < 0x3FFFu && s0 != vslot) ? ((m0 << 13) | (s0 << 6) | Lv) : 0xFFFFFFFFu;
        u32 k1 = (m1 < 0x3FFFu && s1 != vslot) ? ((m1 << 13) | (s1 << 6) | Lv) : 0xFFFFFFFFu;
        u32 rowMin = k0 < k1 ? k0 : k1;
        // ---- two concurrent DPP chains: R = row-Lv rescan, C = cached mins ----
        u32 R = dpp_min_u32(rowMin);
        u32 xc = ((u32)lane == Lv) ? patch : cmin;
        u32 C = dpp_min_u32(xc);
        u32 Rs = (u32)__builtin_amdgcn_readlane((int)R, 63);
        u32 Cs = (u32)__builtin_amdgcn_readlane((int)C, 63);
        u32 g = Rs < Cs ? Rs : Cs;
        if ((u32)lane == Lv) cmin = Rs < patch ? Rs : patch;  // restore exactness
        if (g >= (0x3FFFu << 13)) { if (lane == 0) atomicOr(&ctr[2], 2u); break; }
        if (lane == 0) seqv[step] = g;
        // ---- mark popped vertex in tree (branchless bitmap update) ----
        v = g & 8191u; Lv = v & 63u;
        u32 nslot = v >> 6;
        bool mine = ((u32)lane == Lv);
        u64 bit = 1ull << (nslot & 63u);
        ins0 |= (mine && nslot < 64u) ? bit : 0ull;
        ins1 |= (mine && nslot >= 64u) ? bit : 0ull;
        if (mine) sMind32[(Lv << 7) + nslot] = 0xFFFFFFFFu;
    }
#undef PROC
}

// ---------------- gather: deaths = sqrt(d2 of popped rank) ---------------------
__global__ void gather_kernel(const u32* __restrict__ seqv,
                              const u32* __restrict__ sortedWB,
                              float* __restrict__ out) {
    int s = blockIdx.x * blockDim.x + threadIdx.x;
    if (s < N - 1) {
        u32 p = seqv[s];
        u32 rk = p >> 13;
        out[2 * s + 1] = sqrtf(__uint_as_float(sortedWB[rk]));
    }
}

extern "C" void kernel_launch(void* const* d_in, const int* in_sizes, int n_in,
                              void* d_out, int out_size, void* d_ws, size_t ws_size,
                              hipStream_t stream) {
    const float* x = (const float*)d_in[0];
    float* out = (float*)d_out;

    char* ws = (char*)d_ws;
    size_t o = 0;
    u64* bestR    = (u64*)(ws + o); o += 8192 * 8;            // 64 KB
    u64* bestC    = (u64*)(ws + o); o += 8192 * 8;            // 64 KB
    u64* mstKeys  = (u64*)(ws + o); o += 8192 * 8;            // 64 KB
    u64* edges    = (u64*)(ws + o); o += (size_t)CAP_E * 8;   // 16 MB
    float* norms  = (float*)(ws + o); o += 8192 * 4;
    u32* sortedWB = (u32*)(ws + o); o += 8192 * 4;
    u32* deg      = (u32*)(ws + o); o += 8192 * 4;
    u32* offs     = (u32*)(ws + o); o += 8200 * 4;
    u32* cur      = (u32*)(ws + o); o += 8192 * 4;
    u32* seqv     = (u32*)(ws + o); o += 8192 * 4;
    u32* adj      = (u32*)(ws + o); o += (size_t)CAP_E * 2 * 4; // 16 MB
    uint4* adj4   = (uint4*)(ws + o); o += 8192 * 16;         // 128 KB
    u64* ovf      = (u64*)(ws + o); o += 8192 * 8;            // 64 KB
    u16* comp16   = (u16*)(ws + o); o += 8192 * 2;
    u32* ctr      = (u32*)(ws + o); o += 256;
    // total ~33 MB << 256 MiB

    zero_out_kernel<<<(out_size + 255) / 256, 256, 0, stream>>>(out, out_size);
    norms_kernel<<<32, 256, 0, stream>>>(x, norms);
    init_kernel<<<32, 256, 0, stream>>>(bestR, bestC, comp16, deg, ctr);

    for (int r = 0; r < 13; r++) {
        scan_fused<<<dim3(128, 128), 256, 0, stream>>>(x, norms, comp16, bestR, ctr);
        fold_kernel<<<32, 256, 0, stream>>>(bestR, bestC, comp16, ctr);
        merge_kernel<<<1, 1024, 0, stream>>>(comp16, bestC, mstKeys, ctr);
    }

    sort_kernel<<<1, 1024, 0, stream>>>(mstKeys, sortedWB, ctr);
    collect_kernel<<<dim3(128, 128), 256, 0, stream>>>(x, norms, sortedWB, edges, ctr);
    degcnt_kernel<<<512, 256, 0, stream>>>(edges, deg, ctr);
    offs_kernel<<<1, 1024, 0, stream>>>(deg, offs, cur);
    fill_kernel<<<512, 256, 0, stream>>>(edges, cur, adj, ctr);
    adj4_kernel<<<32, 256, 0, stream>>>(offs, adj, adj4, ovf);
    gprim_kernel<<<1, 256, 0, stream>>>(adj4, ovf, adj, seqv, ctr);
    gather_kernel<<<32, 256, 0, stream>>>(seqv, sortedWB, out);
}